// Round 14
// baseline (554.601 us; speedup 1.0000x reference)
//
#include <hip/hip_runtime.h>
#include <hip/hip_bf16.h>

#define NN   8192
#define NE   262144
#define HD   256
#define NHH  8194   // hh rows = N + 2

using f32x4  = __attribute__((ext_vector_type(4))) float;
using bf16x8 = __attribute__((ext_vector_type(8))) short;
typedef unsigned short u16;

#define GAS(p) ((const __attribute__((address_space(1))) void*)(p))
#define LAS(p) ((__attribute__((address_space(3))) void*)(p))

__device__ __forceinline__ u16 f2bf(float f) {
    unsigned u = __builtin_bit_cast(unsigned, f);
    u = (u + 0x7FFFu + ((u >> 16) & 1u)) >> 16;
    return (u16)u;
}
__device__ __forceinline__ float bf2f(u16 h) {
    return __builtin_bit_cast(float, (unsigned)h << 16);
}
__device__ __forceinline__ void split1(float a, u16& h, u16& l) {
    h = f2bf(a);
    l = f2bf(a - bf2f(h));   // a - hi is exact in fp32
}
__device__ __forceinline__ void store_split4(u16* hi, u16* lo, size_t off, float4 v) {
    ushort4 h, l;
    split1(v.x, h.x, l.x); split1(v.y, h.y, l.y);
    split1(v.z, h.z, l.z); split1(v.w, h.w, l.w);
    *(ushort4*)(hi + off) = h;
    *(ushort4*)(lo + off) = l;
}
__device__ __forceinline__ void add4(float4& a, float4 b) {
    a.x += b.x; a.y += b.y; a.z += b.z; a.w += b.w;
}

// ---------------------------------------------------------------- CSR build
__global__ void hist_kernel(const int* __restrict__ dst, int* __restrict__ cnt, int E) {
    int e = blockIdx.x * blockDim.x + threadIdx.x;
    if (e < E) atomicAdd(&cnt[dst[e]], 1);
}

__global__ __launch_bounds__(1024) void scan_kernel(const int* __restrict__ cnt, int* __restrict__ row_ptr) {
    __shared__ int sdata[1024];
    int tid = threadIdx.x;
    int v[8], local[8];
    int s = 0;
#pragma unroll
    for (int i = 0; i < 8; i++) v[i] = cnt[tid * 8 + i];
#pragma unroll
    for (int i = 0; i < 8; i++) { local[i] = s; s += v[i]; }
    sdata[tid] = s;
    __syncthreads();
    for (int off = 1; off < 1024; off <<= 1) {
        int t = (tid >= off) ? sdata[tid - off] : 0;
        __syncthreads();
        sdata[tid] += t;
        __syncthreads();
    }
    int base = (tid == 0) ? 0 : sdata[tid - 1];
#pragma unroll
    for (int i = 0; i < 8; i++) row_ptr[tid * 8 + i] = base + local[i];
    if (tid == 1023) row_ptr[8192] = sdata[1023];
}

__global__ void copy_int_kernel(const int* __restrict__ a, int* __restrict__ b, int n) {
    int i = blockIdx.x * blockDim.x + threadIdx.x;
    if (i < n) b[i] = a[i];
}

__global__ void fill_kernel(const int* __restrict__ dst, const int* __restrict__ src,
                            int* __restrict__ cursor, int* __restrict__ eids,
                            int* __restrict__ gsrc, int E) {
    int e = blockIdx.x * blockDim.x + threadIdx.x;
    if (e < E) {
        int pos = atomicAdd(&cursor[dst[e]], 1);
        eids[pos] = e;
        gsrc[pos] = src[e];
    }
}

// ---------------------------------------------- fused fp32 -> bf16x2 splits
struct SplitArgs {
    const float* src[11];
    u16* hi[11];
    u16* lo[11];
    int  off[12];
};
__global__ __launch_bounds__(256) void multisplit_kernel(SplitArgs a) {
    int blk = blockIdx.x;
    int s = 0;
#pragma unroll
    for (int t = 0; t < 11; ++t) if (blk >= a.off[t + 1]) s = t + 1;
    size_t i = ((size_t)(blk - a.off[s]) * 256 + threadIdx.x) * 4;
    float4 v = *(const float4*)(a.src[s] + i);
    store_split4(a.hi[s], a.lo[s], i, v);
}

// transpose + split: out[c][r] planes from W[r][c]
__global__ void wtrans_split_kernel(const float* __restrict__ W, u16* __restrict__ outh,
                                    u16* __restrict__ outl, int R, int Cc) {
    int j = blockIdx.x * 256 + threadIdx.x;
    if (j >= R * Cc) return;
    int r = j % R, c = j / R;
    u16 h, l;
    split1(W[(size_t)r * Cc + c], h, l);
    outh[j] = h; outl[j] = l;
}

// ------------------- L2-blocked wave-per-node segment sums (128-feat halves)
// 2 edge slots x 8-deep: 16 gather loads in flight per wave.
struct SegDuo {
    const float* T0; u16* oh0; u16* ol0; int self0;
    const float* T1; u16* oh1; u16* ol1; int self1; int nb0;
};
__global__ __launch_bounds__(256) void segsum128_wave_kernel(const int* __restrict__ row_ptr,
                                                             const int* __restrict__ idx,
                                                             SegDuo a) {
    int blk  = blockIdx.x;
    int seg  = blk / a.nb0;              // 0..3
    int lblk = blk - seg * a.nb0;
    const float* T; u16* oh; u16* ol; int self;
    if (seg >> 1) { T = a.T1; oh = a.oh1; ol = a.ol1; self = a.self1; }
    else          { T = a.T0; oh = a.oh0; ol = a.ol0; self = a.self0; }
    const int half = seg & 1;
    const int n    = lblk * 4 + (threadIdx.x >> 6);
    const int lane = threadIdx.x & 63;
    const int slot = lane >> 5;          // 0/1
    const size_t fo = (size_t)half * 128 + (size_t)(lane & 31) * 4;
    const int b = row_ptr[n], e = row_ptr[n + 1];
    float4 z4 = make_float4(0.f, 0.f, 0.f, 0.f);
    float4 a0 = z4, a1 = z4, a2 = z4, a3 = z4;
    float4 a4 = z4, a5 = z4, a6 = z4, a7 = z4;
    int i = b + slot;
    for (; i + 14 < e; i += 16) {        // this slot: edges i, i+2, ..., i+14
        int s0 = idx[i],      s1 = idx[i + 2],  s2 = idx[i + 4],  s3 = idx[i + 6];
        int s4 = idx[i + 8],  s5 = idx[i + 10], s6 = idx[i + 12], s7 = idx[i + 14];
        add4(a0, *(const float4*)(T + (size_t)s0 * HD + fo));
        add4(a1, *(const float4*)(T + (size_t)s1 * HD + fo));
        add4(a2, *(const float4*)(T + (size_t)s2 * HD + fo));
        add4(a3, *(const float4*)(T + (size_t)s3 * HD + fo));
        add4(a4, *(const float4*)(T + (size_t)s4 * HD + fo));
        add4(a5, *(const float4*)(T + (size_t)s5 * HD + fo));
        add4(a6, *(const float4*)(T + (size_t)s6 * HD + fo));
        add4(a7, *(const float4*)(T + (size_t)s7 * HD + fo));
    }
    for (; i < e; i += 2) {
        int s0 = idx[i];
        add4(a0, *(const float4*)(T + (size_t)s0 * HD + fo));
    }
    if (self && slot == 0) add4(a1, *(const float4*)(T + (size_t)n * HD + fo));
    add4(a0, a1); add4(a2, a3); add4(a4, a5); add4(a6, a7);
    add4(a0, a2); add4(a4, a6); add4(a0, a4);
    a0.x += __shfl_xor(a0.x, 32); a0.y += __shfl_xor(a0.y, 32);
    a0.z += __shfl_xor(a0.z, 32); a0.w += __shfl_xor(a0.w, 32);
    if (slot == 0) store_split4(oh, ol, (size_t)n * HD + fo, a0);
}

// 64-feat: wave per node, 4 edge-groups of 16 lanes, shfl_xor reduce.
__global__ __launch_bounds__(256) void segsum64_wave_kernel(const int* __restrict__ row_ptr,
                                                            const int* __restrict__ idx,
                                                            const float* __restrict__ T,
                                                            u16* __restrict__ outh,
                                                            u16* __restrict__ outl) {
    const int n    = blockIdx.x * 4 + (threadIdx.x >> 6);
    const int lane = threadIdx.x & 63;
    const int g    = lane >> 4;
    const size_t fo = (size_t)(lane & 15) * 4;
    const int b = row_ptr[n], e = row_ptr[n + 1];
    float4 a0 = make_float4(0.f, 0.f, 0.f, 0.f);
    float4 a1 = a0;
    int i = b + g;
    for (; i + 4 < e; i += 8) {
        int s0 = idx[i], s1 = idx[i + 4];
        add4(a0, *(const float4*)(T + (size_t)s0 * 64 + fo));
        add4(a1, *(const float4*)(T + (size_t)s1 * 64 + fo));
    }
    if (i < e) {
        int s0 = idx[i];
        add4(a0, *(const float4*)(T + (size_t)s0 * 64 + fo));
    }
    add4(a0, a1);
    a0.x += __shfl_xor(a0.x, 16); a0.y += __shfl_xor(a0.y, 16);
    a0.z += __shfl_xor(a0.z, 16); a0.w += __shfl_xor(a0.w, 16);
    a0.x += __shfl_xor(a0.x, 32); a0.y += __shfl_xor(a0.y, 32);
    a0.z += __shfl_xor(a0.z, 32); a0.w += __shfl_xor(a0.w, 32);
    if (g == 0) store_split4(outh, outl, (size_t)n * 64 + fo, a0);
}

// ---------------- batched LDS-staged split-bf16 3-product MFMA GEMM
// 128x64 C-tile, 4 waves of 64x32. BK=64. LDS stride 64 u16 + XOR swizzle.
// Staging via global_load_lds width=16 with pre-swizzled global source (m173).
// flags: 1 = relu, 2 = accumulate into C (skip bias)
struct GDesc {
    const u16 *Ah, *Al, *Abh, *Abl, *Wh, *Wl;
    const float* bias;
    float* C; u16 *Chi, *Clo;
    int lda, ldab, Ka, Kb, ldw, ldc, M, flags, nbx, nblk;
};
struct GBatch { GDesc d[3]; int start[4]; };

#define LDSA0 0
#define LDSA1 8192
#define LDSW0 16384
#define LDSW1 20480
__global__ __launch_bounds__(256) void hgemm_kernel(GBatch b) {
    __shared__ __align__(16) u16 lds[24576];
    int s = (blockIdx.x >= (unsigned)b.start[1]) + (blockIdx.x >= (unsigned)b.start[2]);
    GDesc d = b.d[0];
    if (s == 1) d = b.d[1];
    else if (s == 2) d = b.d[2];

    // local bijective XCD swizzle within this desc's block range
    int nwg = b.start[s + 1] - b.start[s];
    int o   = blockIdx.x - b.start[s];
    int q = nwg >> 3, r = nwg & 7;
    int xcd = o & 7;
    int base = (xcd < r) ? xcd * (q + 1) : r * (q + 1) + (xcd - r) * q;
    int wg = base + (o >> 3);
    int bx = wg % d.nbx, by = wg / d.nbx;

    const int tid  = threadIdx.x;
    const int wid  = tid >> 6;
    const int lane = tid & 63;
    const int lrow = lane & 15;
    const int ksel = lane >> 4;
    const int rswz = (lrow & 7) << 3;

    // gload_lds staging geometry: chunk j = i*256 + tid; row=j>>3; c_dst=lane&7
    const int arow_l = wid * 8 + (lane >> 3);            // + i*32 per issue
    const int csrc8  = ((lane & 7) ^ ((lane >> 3) & 7)) * 8;  // u16 offset of source chunk

    const int nt = (d.Ka + d.Kb) >> 6;

    auto stage = [&](int t) {
        int kb = t << 6;
        const u16 *ph, *pl; int ld_; int kk;
        if (kb < d.Ka) { ph = d.Ah;  pl = d.Al;  ld_ = d.lda;  kk = kb; }
        else           { ph = d.Abh; pl = d.Abl; ld_ = d.ldab; kk = kb - d.Ka; }
#pragma unroll
        for (int i = 0; i < 4; ++i) {
            int row = i * 32 + arow_l;
            int rg  = min(by * 128 + row, d.M - 1);
            const u16* gah = ph + (size_t)rg * ld_ + kk + csrc8;
            const u16* gal = pl + (size_t)rg * ld_ + kk + csrc8;
            char* ba = (char*)lds + i * 4096 + wid * 1024;
            __builtin_amdgcn_global_load_lds(GAS(gah), LAS(ba), 16, 0, 0);
            __builtin_amdgcn_global_load_lds(GAS(gal), LAS(ba + LDSA1 * 2), 16, 0, 0);
        }
#pragma unroll
        for (int i = 0; i < 2; ++i) {
            int row = i * 32 + arow_l;
            size_t wo = (size_t)(bx * 64 + row) * d.ldw + kb + csrc8;
            const u16* gwh = d.Wh + wo;
            const u16* gwl = d.Wl + wo;
            char* bw = (char*)lds + LDSW0 * 2 + i * 4096 + wid * 1024;
            __builtin_amdgcn_global_load_lds(GAS(gwh), LAS(bw), 16, 0, 0);
            __builtin_amdgcn_global_load_lds(GAS(gwl), LAS(bw + (LDSW1 - LDSW0) * 2), 16, 0, 0);
        }
    };

    f32x4 acc[4][2] = {};
    const int fr0 = (wid >> 1) * 64;
    const int cr0 = (wid & 1) * 32;

    for (int t = 0; t < nt; ++t) {
        stage(t);
        __syncthreads();          // drains vmcnt -> LDS tile ready
#pragma unroll
        for (int ks = 0; ks < 2; ++ks) {
            bf16x8 fah[4], fal[4], fwh[2], fwl[2];
            const int ko = (ks * 32 + ksel * 8) ^ rswz;
#pragma unroll
            for (int fi = 0; fi < 4; ++fi) {
                int oo = (fr0 + fi * 16 + lrow) * 64 + ko;
                fah[fi] = *(const bf16x8*)(lds + LDSA0 + oo);
                fal[fi] = *(const bf16x8*)(lds + LDSA1 + oo);
            }
#pragma unroll
            for (int ci = 0; ci < 2; ++ci) {
                int oo = (cr0 + ci * 16 + lrow) * 64 + ko;
                fwh[ci] = *(const bf16x8*)(lds + LDSW0 + oo);
                fwl[ci] = *(const bf16x8*)(lds + LDSW1 + oo);
            }
#pragma unroll
            for (int fi = 0; fi < 4; ++fi)
#pragma unroll
                for (int ci = 0; ci < 2; ++ci) {
                    acc[fi][ci] = __builtin_amdgcn_mfma_f32_16x16x32_bf16(fah[fi], fwh[ci], acc[fi][ci], 0, 0, 0);
                    acc[fi][ci] = __builtin_amdgcn_mfma_f32_16x16x32_bf16(fah[fi], fwl[ci], acc[fi][ci], 0, 0, 0);
                    acc[fi][ci] = __builtin_amdgcn_mfma_f32_16x16x32_bf16(fal[fi], fwh[ci], acc[fi][ci], 0, 0, 0);
                }
        }
        __syncthreads();          // all reads done before next stage overwrites
    }

#pragma unroll
    for (int fi = 0; fi < 4; ++fi) {
        int rbase = by * 128 + fr0 + fi * 16 + (lane >> 4) * 4;
#pragma unroll
        for (int ci = 0; ci < 2; ++ci) {
            int col = bx * 64 + cr0 + ci * 16 + lrow;
#pragma unroll
            for (int j = 0; j < 4; ++j) {
                int rr = rbase + j;
                if (rr >= d.M) continue;
                float v = acc[fi][ci][j];
                size_t oo = (size_t)rr * d.ldc + col;
                if (d.flags & 2)    v += d.C[oo];
                else if (d.bias)    v += d.bias[col];
                if (d.flags & 1)    v = fmaxf(v, 0.f);
                if (d.C) d.C[oo] = v;
                if (d.Chi) { u16 hb, lb; split1(v, hb, lb); d.Chi[oo] = hb; d.Clo[oo] = lb; }
            }
        }
    }
}

// ----------------------------------------------------------- GRU elementwise
__global__ void gru_combine_kernel(const float* __restrict__ gi, const float* __restrict__ gh,
                                   const float* __restrict__ hprev, float* __restrict__ hout,
                                   u16* __restrict__ hhi, u16* __restrict__ hlo, int total4) {
    int t = blockIdx.x * 256 + threadIdx.x;
    if (t >= total4) return;
    int i4  = t * 4;
    int row = i4 >> 8, f = i4 & 255;
    size_t b = (size_t)row * 768;
    float4 ir = *(const float4*)(gi + b + f);
    float4 iz = *(const float4*)(gi + b + 256 + f);
    float4 in_ = *(const float4*)(gi + b + 512 + f);
    float4 hr = *(const float4*)(gh + b + f);
    float4 hz = *(const float4*)(gh + b + 256 + f);
    float4 hn = *(const float4*)(gh + b + 512 + f);
    float4 hp = *(const float4*)(hprev + (size_t)row * HD + f);
    float4 hv;
#pragma unroll
    for (int j = 0; j < 4; ++j) {
        float irj = ((const float*)&ir)[j], izj = ((const float*)&iz)[j], inj = ((const float*)&in_)[j];
        float hrj = ((const float*)&hr)[j], hzj = ((const float*)&hz)[j], hnj = ((const float*)&hn)[j];
        float r = 1.f / (1.f + expf(-(irj + hrj)));
        float z = 1.f / (1.f + expf(-(izj + hzj)));
        float n = tanhf(inj + r * hnj);
        ((float*)&hv)[j] = (1.f - z) * n + z * ((const float*)&hp)[j];
    }
    size_t o = (size_t)row * HD + f;
    *(float4*)(hout + o) = hv;
    if (hhi) store_split4(hhi, hlo, o, hv);
}

// ------------------------------------------------------------------ epilogue
__global__ void hhtail_kernel(const float* __restrict__ rc, const float* __restrict__ si,
                              float* __restrict__ hh, u16* __restrict__ hhi, u16* __restrict__ hlo) {
    int f = threadIdx.x;
    size_t o1 = (size_t)NN * HD + f, o2 = (size_t)(NN + 1) * HD + f;
    float a = rc[f], b = si[f];
    hh[o1] = a; hh[o2] = b;
    u16 h, l;
    split1(a, h, l); hhi[o1] = h; hlo[o1] = l;
    split1(b, h, l); hhi[o2] = h; hlo[o2] = l;
}

__global__ __launch_bounds__(256) void alpha_kernel(const float* __restrict__ g1, const float* __restrict__ gw2,
                                                    const float* __restrict__ gb2, const int* __restrict__ rcmask,
                                                    float* __restrict__ coef, int N) {
    int node = blockIdx.x * 4 + (threadIdx.x >> 6);
    int lane = threadIdx.x & 63;
    if (node >= N) return;
    float part = g1[(size_t)node * 128 + lane] * gw2[lane]
               + g1[(size_t)node * 128 + 64 + lane] * gw2[64 + lane];
    for (int off = 32; off > 0; off >>= 1) part += __shfl_down(part, off);
    if (lane == 0) {
        float a = 1.f / (1.f + expf(-(part + gb2[0])));
        coef[node] = rcmask[node] ? 0.f : a;
    }
}

__global__ __launch_bounds__(256) void colsum_kernel(const float* __restrict__ X, const float* __restrict__ coef,
                                                     float* __restrict__ out, int rows_total, int rows_per_blk) {
    int f  = threadIdx.x;
    int r0 = blockIdx.x * rows_per_blk;
    int r1 = r0 + rows_per_blk; if (r1 > rows_total) r1 = rows_total;
    float a0 = 0.f, a1 = 0.f;
    int r = r0;
    for (; r + 1 < r1; r += 2) {
        a0 += coef[r]     * X[(size_t)r * HD + f];
        a1 += coef[r + 1] * X[(size_t)(r + 1) * HD + f];
    }
    if (r < r1) a0 += coef[r] * X[(size_t)r * HD + f];
    atomicAdd(&out[f], a0 + a1);
}

__global__ __launch_bounds__(256) void gemv256_kernel(const float* __restrict__ M,
                                                      const float* __restrict__ vA,
                                                      const float* __restrict__ vB,
                                                      const float* __restrict__ bias,
                                                      float* __restrict__ out, int R) {
    int row  = blockIdx.x * 4 + (threadIdx.x >> 6);
    int lane = threadIdx.x & 63;
    if (row >= R) return;
    float4 v = *(const float4*)(vA + lane * 4);
    if (vB) {
        float4 b = *(const float4*)(vB + lane * 4);
        v.x += b.x; v.y += b.y; v.z += b.z; v.w += b.w;
    }
    float4 m = *(const float4*)(M + (size_t)row * 256 + lane * 4);
    float p = m.x * v.x + m.y * v.y + m.z * v.z + m.w * v.w;
    for (int off = 32; off > 0; off >>= 1) p += __shfl_down(p, off);
    if (lane == 0) out[row] = p + (bias ? bias[row] : 0.f);
}

__global__ void sgru_combine_kernel(const float* __restrict__ gi3, const float* __restrict__ gh3,
                                    const float* __restrict__ sinit,
                                    float* __restrict__ hh, u16* __restrict__ hhi, u16* __restrict__ hlo) {
    int f = threadIdx.x;
    float gir = gi3[f], giz = gi3[256 + f], gin_ = gi3[512 + f];
    float ghr = gh3[f], ghz = gh3[256 + f], ghn  = gh3[512 + f];
    float r = 1.f / (1.f + expf(-(gir + ghr)));
    float z = 1.f / (1.f + expf(-(giz + ghz)));
    float n = tanhf(gin_ + r * ghn);
    float hv = (1.f - z) * n + z * sinit[f];
    size_t o = (size_t)(NN + 1) * HD + f;
    hh[o] = hv;
    u16 h, l; split1(hv, h, l); hhi[o] = h; hlo[o] = l;
}

__global__ __launch_bounds__(256) void logits_kernel(const float* __restrict__ kall, const float* __restrict__ qrow,
                                                     float* __restrict__ logits, int n) {
    int j    = blockIdx.x * 4 + (threadIdx.x >> 6);
    int lane = threadIdx.x & 63;
    if (j >= n) return;
    float4 q = *(const float4*)(qrow + lane * 4);
    float4 k = *(const float4*)(kall + (size_t)j * HD + lane * 4);
    float part = q.x * k.x + q.y * k.y + q.z * k.z + q.w * k.w;
    for (int off = 32; off > 0; off >>= 1) part += __shfl_down(part, off);
    if (lane == 0) logits[j] = part * 0.0625f;
}

__global__ __launch_bounds__(1024) void softmax_prep_kernel(const float* __restrict__ logits, float* __restrict__ p,
                                                            float* __restrict__ scal, int n) {
    __shared__ float sd[1024];
    int tid = threadIdx.x;
    float mx = -1e30f;
    for (int j = tid; j < n; j += 1024) mx = fmaxf(mx, logits[j]);
    sd[tid] = mx;
    __syncthreads();
    for (int off = 512; off > 0; off >>= 1) { if (tid < off) sd[tid] = fmaxf(sd[tid], sd[tid + off]); __syncthreads(); }
    float m = sd[0];
    __syncthreads();
    float s = 0.f;
    for (int j = tid; j < n; j += 1024) { float e = expf(logits[j] - m); p[j] = e; s += e; }
    sd[tid] = s;
    __syncthreads();
    for (int off = 512; off > 0; off >>= 1) { if (tid < off) sd[tid] += sd[tid + off]; __syncthreads(); }
    if (tid == 0) scal[0] = sd[0];
}

__global__ __launch_bounds__(256) void final_gemv_kernel(const float* __restrict__ hh,
                                                         const float* __restrict__ ow,
                                                         const float* __restrict__ ob,
                                                         const float* __restrict__ ctx,
                                                         const float* __restrict__ scal,
                                                         float* __restrict__ out) {
    int row  = blockIdx.x * 4 + (threadIdx.x >> 6);
    int lane = threadIdx.x & 63;
    float4 c = *(const float4*)(ctx + lane * 4);
    float4 m = *(const float4*)(ow + (size_t)row * 256 + lane * 4);
    float p = m.x * c.x + m.y * c.y + m.z * c.z + m.w * c.w;
    for (int off = 32; off > 0; off >>= 1) p += __shfl_down(p, off);
    if (lane == 0) {
        float val = hh[(size_t)(NN + 1) * HD + row] + p / scal[0] + ob[row];
        out[row] = fmaxf(val, 0.f);
    }
}

// ---------------------------------------------------------------------------
extern "C" void kernel_launch(void* const* d_in, const int* in_sizes, int n_in,
                              void* d_out, int out_size, void* d_ws, size_t ws_size,
                              hipStream_t stream) {
    const float* x      = (const float*)d_in[0];
    const int*   ei     = (const int*)  d_in[1];
    const float* eattr  = (const float*)d_in[2];
    const int*   rcmask = (const int*)  d_in[3];
    const float* Wmsg1  = (const float*)d_in[4];
    const float* wih1   = (const float*)d_in[5];
    const float* whh1   = (const float*)d_in[6];
    const float* bih1   = (const float*)d_in[7];
    const float* bhh1   = (const float*)d_in[8];
    const float* Wmsg2  = (const float*)d_in[9];
    const float* wih2   = (const float*)d_in[10];
    const float* whh2   = (const float*)d_in[11];
    const float* bih2   = (const float*)d_in[12];
    const float* bhh2   = (const float*)d_in[13];
    const float* ginw1  = (const float*)d_in[14];
    const float* ginb1  = (const float*)d_in[15];
    const float* ginw2  = (const float*)d_in[16];
    const float* ginb2  = (const float*)d_in[17];
    const float* projw  = (const float*)d_in[18];
    const float* projb  = (const float*)d_in[19];
    const float* qw     = (const float*)d_in[20];
    const float* qb     = (const float*)d_in[21];
    const float* kw     = (const float*)d_in[22];
    const float* kb     = (const float*)d_in[23];
    const float* vw     = (const float*)d_in[24];
    const float* vb     = (const float*)d_in[25];
    const float* ow     = (const float*)d_in[26];
    const float* ob     = (const float*)d_in[27];
    const float* gatew1 = (const float*)d_in[28];
    const float* gateb1 = (const float*)d_in[29];
    const float* gatew2 = (const float*)d_in[30];
    const float* gateb2 = (const float*)d_in[31];
    const float* skipW  = (const float*)d_in[32];
    const float* swih   = (const float*)d_in[33];
    const float* swhh   = (const float*)d_in[34];
    const float* sbih   = (const float*)d_in[35];
    const float* sbhh   = (const float*)d_in[36];
    const float* rcinit = (const float*)d_in[37];
    const float* sinit  = (const float*)d_in[38];

    const int* src = ei;
    const int* dst = ei + NE;

    // ---------------- workspace layout -------------------------------------
    char*  w   = (char*)d_ws;
    size_t off = 0;
    auto alloc = [&](size_t bytes) -> void* {
        void* p = w + off;
        off = (off + bytes + 255) & ~(size_t)255;
        return p;
    };
    int*   cnt     = (int*)alloc((size_t)NN * 4);
    int*   row_ptr = (int*)alloc((size_t)(NN + 1) * 4);
    int*   eids    = (int*)alloc((size_t)NE * 4);
    int*   gsrc    = (int*)alloc((size_t)NE * 4);
    u16*   aeh     = (u16*)alloc((size_t)NN * 64 * 2);
    u16*   ael     = (u16*)alloc((size_t)NN * 64 * 2);
    u16*   shh_    = (u16*)alloc((size_t)NHH * HD * 2);    // x / hh planes
    u16*   shl_    = (u16*)alloc((size_t)NHH * HD * 2);
    u16*   gsh     = (u16*)alloc((size_t)NN * HD * 2);
    u16*   gsl     = (u16*)alloc((size_t)NN * HD * 2);
    u16*   gs2h    = (u16*)alloc((size_t)NN * HD * 2);
    u16*   gs2l    = (u16*)alloc((size_t)NN * HD * 2);
    u16*   msh     = (u16*)alloc((size_t)NN * HD * 2);
    u16*   msl     = (u16*)alloc((size_t)NN * HD * 2);
    u16*   ms2h    = (u16*)alloc((size_t)NN * HD * 2);
    u16*   ms2l    = (u16*)alloc((size_t)NN * HD * 2);
    float* h1      = (float*)alloc((size_t)NN * HD * 4);
    float* h2      = (float*)alloc((size_t)NN * HD * 4);
    float* gi      = (float*)alloc((size_t)NN * 768 * 4);  // gi fp32
    float* gh      = (float*)alloc((size_t)NN * 768 * 4);  // gh fp32; u768 planes / scratch / k,v
    float* hh      = (float*)alloc((size_t)NHH * HD * 4);
    float* coef    = (float*)alloc((size_t)NN * 4);
    float* wsum    = (float*)alloc(256 * 4);
    float* qrow    = (float*)alloc(256 * 4);
    float* logits  = (float*)alloc((size_t)NHH * 4);
    float* pbuf    = (float*)alloc((size_t)NHH * 4);
    float* scal    = (float*)alloc(256);
    float* ctx     = (float*)alloc(256 * 4);
    float* mvec    = (float*)alloc(256 * 4);
    float* gi3     = (float*)alloc(768 * 4);
    float* gh3     = (float*)alloc(768 * 4);

    auto walloc = [&](size_t nel, u16** h, u16** l) {
        *h = (u16*)alloc(nel * 2); *l = (u16*)alloc(nel * 2);
    };
    u16 *wm1Th, *wm1Tl, *wm2Th, *wm2Tl;
    u16 *wc1h, *wc1l, *wc2h, *wc2l;
    u16 *wi1h, *wi1l, *wh1h, *wh1l, *wi2h, *wi2l, *wh2h, *wh2l;
    u16 *g1h, *g1l, *g2h, *g2l, *pjh, *pjl, *gwh, *gwl, *kwh, *kwl, *vwh, *vwl;
    walloc(81920, &wm1Th, &wm1Tl); walloc(81920, &wm2Th, &wm2Tl);
    walloc(245760, &wc1h, &wc1l);  walloc(245760, &wc2h, &wc2l);
    walloc(196608, &wi1h, &wi1l);  walloc(196608, &wh1h, &wh1l);
    walloc(196608, &wi2h, &wi2l);  walloc(196608, &wh2h, &wh2l);
    walloc(196608, &g1h, &g1l);    walloc(196608, &g2h, &g2l);
    walloc(196608, &pjh, &pjl);    walloc(32768, &gwh, &gwl);
    walloc(65536, &kwh, &kwl);     walloc(65536, &vwh, &vwl);
    u16 *xh = shh_, *xl = shl_;

    // phase aliases (gh region: fp32 in DMPNN; u768 planes then scratch in GIN; k/v late)
    u16*   u768h = (u16*)gh;
    u16*   u768l = u768h + (size_t)NN * 768;
    u16*   sAh   = (u16*)gh;                       // scratch planes after u768 dead
    u16*   sAl   = sAh + (size_t)NN * HD;
    u16*   sBh   = sAh + (size_t)2 * NN * HD;
    u16*   sBl   = sAh + (size_t)3 * NN * HD;
    float* k_all = gh;
    float* v_all = gh + (size_t)NHH * HD;
    float* g1    = gh + (size_t)2 * NHH * HD;

    auto mkd = [&](const u16* Ah, const u16* Al, int lda,
                   const u16* Abh, const u16* Abl, int ldab, int Ka, int Kb,
                   const u16* Wh, const u16* Wl, int ldw, const float* bias,
                   float* C, u16* Chi, u16* Clo, int ldc,
                   int M, int Nc, int flags) -> GDesc {
        GDesc d;
        d.Ah = Ah; d.Al = Al; d.Abh = Abh; d.Abl = Abl; d.Wh = Wh; d.Wl = Wl;
        d.bias = bias; d.C = C; d.Chi = Chi; d.Clo = Clo;
        d.lda = lda; d.ldab = ldab; d.Ka = Ka; d.Kb = Kb; d.ldw = ldw; d.ldc = ldc;
        d.M = M; d.flags = flags; d.nbx = Nc / 64;
        d.nblk = d.nbx * ((M + 127) / 128);
        return d;
    };
    auto hg1 = [&](GDesc d0) {
        GBatch b; b.d[0] = d0; b.d[1] = d0; b.d[2] = d0;
        b.start[0] = 0; b.start[1] = d0.nblk; b.start[2] = d0.nblk; b.start[3] = d0.nblk;
        hgemm_kernel<<<b.start[3], 256, 0, stream>>>(b);
    };
    auto hg2 = [&](GDesc d0, GDesc d1) {
        GBatch b; b.d[0] = d0; b.d[1] = d1; b.d[2] = d1;
        b.start[0] = 0; b.start[1] = d0.nblk; b.start[2] = d0.nblk + d1.nblk; b.start[3] = b.start[2];
        hgemm_kernel<<<b.start[3], 256, 0, stream>>>(b);
    };
    auto hg3 = [&](GDesc d0, GDesc d1, GDesc d2) {
        GBatch b; b.d[0] = d0; b.d[1] = d1; b.d[2] = d2;
        b.start[0] = 0; b.start[1] = d0.nblk; b.start[2] = d0.nblk + d1.nblk;
        b.start[3] = b.start[2] + d2.nblk;
        hgemm_kernel<<<b.start[3], 256, 0, stream>>>(b);
    };
    auto seg1 = [&](const float* T, u16* oh, u16* ol, int self) {
        SegDuo a; a.T0 = T; a.oh0 = oh; a.ol0 = ol; a.self0 = self;
        a.T1 = T; a.oh1 = oh; a.ol1 = ol; a.self1 = self; a.nb0 = NN / 4;
        segsum128_wave_kernel<<<2 * (NN / 4), 256, 0, stream>>>(row_ptr, gsrc, a);
    };
    auto seg2 = [&](const float* T0, u16* oh0, u16* ol0, int s0,
                    const float* T1, u16* oh1, u16* ol1, int s1) {
        SegDuo a; a.T0 = T0; a.oh0 = oh0; a.ol0 = ol0; a.self0 = s0;
        a.T1 = T1; a.oh1 = oh1; a.ol1 = ol1; a.self1 = s1; a.nb0 = NN / 4;
        segsum128_wave_kernel<<<4 * (NN / 4), 256, 0, stream>>>(row_ptr, gsrc, a);
    };

    // ------------------------------ CSR build ------------------------------
    hipMemsetAsync(cnt, 0, (size_t)NN * 4, stream);
    hist_kernel<<<NE / 256, 256, 0, stream>>>(dst, cnt, NE);
    scan_kernel<<<1, 1024, 0, stream>>>(cnt, row_ptr);
    copy_int_kernel<<<NN / 256, 256, 0, stream>>>(row_ptr, cnt, NN);
    fill_kernel<<<NE / 256, 256, 0, stream>>>(dst, src, cnt, eids, gsrc, NE);
    segsum64_wave_kernel<<<NN / 4, 256, 0, stream>>>(row_ptr, eids, eattr, aeh, ael);

    // ------------------------------ one-time splits ------------------------
    {
        SplitArgs a;
        const float* srcs[11] = { x, wih1, whh1, wih2, whh2,
                                  ginw1, ginw2, projw, gatew1, kw, vw };
        u16* his[11] = { xh, wi1h, wh1h, wi2h, wh2h, g1h, g2h, pjh, gwh, kwh, vwh };
        u16* los[11] = { xl, wi1l, wh1l, wi2l, wh2l, g1l, g2l, pjl, gwl, kwl, vwl };
        const int blocks[11] = { 2048, 192, 192, 192, 192, 192, 192, 192, 32, 64, 64 };
        int acc = 0;
        for (int t = 0; t < 11; ++t) { a.src[t] = srcs[t]; a.hi[t] = his[t]; a.lo[t] = los[t]; a.off[t] = acc; acc += blocks[t]; }
        a.off[11] = acc;
        multisplit_kernel<<<acc, 256, 0, stream>>>(a);
    }
    wtrans_split_kernel<<<(81920 + 255) / 256, 256, 0, stream>>>(Wmsg1, wm1Th, wm1Tl, 256, 320);
    wtrans_split_kernel<<<(81920 + 255) / 256, 256, 0, stream>>>(Wmsg2, wm2Th, wm2Tl, 256, 320);
    // Wc = wih @ Wmsg   ([768][320] planes), both layers in one dispatch
    hg2(mkd(wi1h, wi1l, HD, nullptr, nullptr, 0, HD, 0, wm1Th, wm1Tl, HD, nullptr,
            nullptr, wc1h, wc1l, 320, 768, 320, 0),
        mkd(wi2h, wi2l, HD, nullptr, nullptr, 0, HD, 0, wm2Th, wm2Tl, HD, nullptr,
            nullptr, wc2h, wc2l, 320, 768, 320, 0));

    // ------------------------------ DMPNN 1 --------------------------------
    seg1(x, gsh, gsl, 0);
    hg2(mkd(gsh, gsl, HD, aeh, ael, 64, HD, 64, wc1h, wc1l, 320, bih1,
            gi, nullptr, nullptr, 768, NN, 768, 0),
        mkd(shh_, shl_, HD, nullptr, nullptr, 0, HD, 0, wh1h, wh1l, HD, bhh1,
            gh, nullptr, nullptr, 768, NN, 768, 0));
    gru_combine_kernel<<<NN * HD / 1024, 256, 0, stream>>>(gi, gh, x, h1, gs2h, gs2l, NN * HD / 4);

    // ------------------------------ DMPNN 2 --------------------------------
    seg1(h1, gsh, gsl, 0);
    hg2(mkd(gsh, gsl, HD, aeh, ael, 64, HD, 64, wc2h, wc2l, 320, bih2,
            gi, nullptr, nullptr, 768, NN, 768, 0),
        mkd(gs2h, gs2l, HD, nullptr, nullptr, 0, HD, 0, wh2h, wh2l, HD, bhh2,
            gh, nullptr, nullptr, 768, NN, 768, 0));
    gru_combine_kernel<<<NN * HD / 1024, 256, 0, stream>>>(gi, gh, h1, h2, nullptr, nullptr, NN * HD / 4);

    // ------------------------------ GIN towers (proj folded, batched) ------
    seg1(h2, gsh, gsl, 1);
    hg1(mkd(gsh, gsl, HD, nullptr, nullptr, 0, HD, 0, g1h, g1l, HD, ginb1,
            nullptr, u768h, u768l, 768, NN, 768, 1));
    hg3(mkd(u768h, u768l, 768, nullptr, nullptr, 0, HD, 0, g2h, g2l, HD, ginb2,
            nullptr, msh, msl, HD, NN, HD, 0),
        mkd(u768h + 256, u768l + 256, 768, nullptr, nullptr, 0, HD, 0, g2h + 65536, g2l + 65536, HD, ginb2 + 256,
            h1, nullptr, nullptr, HD, NN, HD, 0),
        mkd(u768h + 512, u768l + 512, 768, nullptr, nullptr, 0, HD, 0, g2h + 131072, g2l + 131072, HD, ginb2 + 512,
            h2, nullptr, nullptr, HD, NN, HD, 0));
    // towers 1,2 hop-2 aggregations (u768 now dead -> sA/sB scratch usable)
    seg2(h1, gsh, gsl, 1, h2, gs2h, gs2l, 1);
    // batch: proj slice 0 (reads msh) + g1 for towers 1,2 (write sA, sB)
    hg3(mkd(msh, msl, HD, nullptr, nullptr, 0, HD, 0, pjh, pjl, 768, projb,
            hh, nullptr, nullptr, HD, NN, HD, 0),
        mkd(gsh, gsl, HD, nullptr, nullptr, 0, HD, 0, g1h + 65536, g1l + 65536, HD, ginb1 + 256,
            nullptr, sAh, sAl, HD, NN, HD, 1),
        mkd(gs2h, gs2l, HD, nullptr, nullptr, 0, HD, 0, g1h + 131072, g1l + 131072, HD, ginb1 + 512,
            nullptr, sBh, sBl, HD, NN, HD, 1));
    // g2: tower1 final -> gsh planes, tower2 mid -> h1 fp32
    hg2(mkd(sAh, sAl, HD, nullptr, nullptr, 0, HD, 0, g2h + 65536, g2l + 65536, HD, ginb2 + 256,
            nullptr, gsh, gsl, HD, NN, HD, 0),
        mkd(sBh, sBl, HD, nullptr, nullptr, 0, HD, 0, g2h + 131072, g2l + 131072, HD, ginb2 + 512,
            h1, nullptr, nullptr, HD, NN, HD, 0));
    // tower2 hop-3 agg
    seg1(h1, gs2h, gs2l, 1);
    // batch: proj slice 1 (reads gsh, hh += ) + tower2 g1 (gs2 -> ms2)
    hg2(mkd(gsh, gsl, HD, nullptr, nullptr, 0, HD, 0, pjh + 256, pjl + 256, 768, nullptr,
            hh, nullptr, nullptr, HD, NN, HD, 2),
        mkd(gs2h, gs2l, HD, nullptr, nullptr, 0, HD, 0, g1h + 131072, g1l + 131072, HD, ginb1 + 512,
            nullptr, ms2h, ms2l, HD, NN, HD, 1));
    hg1(mkd(ms2h, ms2l, HD, nullptr, nullptr, 0, HD, 0, g2h + 131072, g2l + 131072, HD, ginb2 + 512,
            nullptr, gs2h, gs2l, HD, NN, HD, 0));
    // proj slice 2: hh += t2f @ projw[:, 512:768]^T ; emit hh planes
    hg1(mkd(gs2h, gs2l, HD, nullptr, nullptr, 0, HD, 0, pjh + 512, pjl + 512, 768, nullptr,
            hh, shh_, shl_, HD, NN, HD, 2));
    hhtail_kernel<<<1, 256, 0, stream>>>(rcinit, sinit, hh, shh_, shl_);

    // ------------------------------ gate / skip-sum / sGRU -----------------
    hg1(mkd(shh_, shl_, HD, nullptr, nullptr, 0, HD, 0, gwh, gwl, HD, gateb1,
            g1, nullptr, nullptr, 128, NN, 128, 1));
    alpha_kernel<<<NN / 4, 256, 0, stream>>>(g1, gatew2, gateb2, rcmask, coef, NN);
    hipMemsetAsync(wsum, 0, 256 * 4, stream);
    colsum_kernel<<<256, 256, 0, stream>>>(hh, coef, wsum, NN, 32);
    gemv256_kernel<<<64, 256, 0, stream>>>(skipW, wsum, rcinit, nullptr, mvec, 256);
    gemv256_kernel<<<192, 256, 0, stream>>>(swih, mvec, nullptr, sbih, gi3, 768);
    gemv256_kernel<<<192, 256, 0, stream>>>(swhh, sinit, nullptr, sbhh, gh3, 768);
    sgru_combine_kernel<<<1, 256, 0, stream>>>(gi3, gh3, sinit, hh, shh_, shl_);

    // ------------------------------ attention row --------------------------
    hg2(mkd(shh_, shl_, HD, nullptr, nullptr, 0, HD, 0, kwh, kwl, HD, kb,
            k_all, nullptr, nullptr, HD, NHH, HD, 0),
        mkd(shh_, shl_, HD, nullptr, nullptr, 0, HD, 0, vwh, vwl, HD, vb,
            v_all, nullptr, nullptr, HD, NHH, HD, 0));
    gemv256_kernel<<<64, 256, 0, stream>>>(qw, hh + (size_t)(NN + 1) * HD, nullptr, qb, qrow, 256);
    logits_kernel<<<(NHH + 3) / 4, 256, 0, stream>>>(k_all, qrow, logits, NHH);
    softmax_prep_kernel<<<1, 1024, 0, stream>>>(logits, pbuf, scal, NHH);
    hipMemsetAsync(ctx, 0, 256 * 4, stream);
    colsum_kernel<<<(NHH + 31) / 32, 256, 0, stream>>>(v_all, pbuf, ctx, NHH, 32);
    final_gemv_kernel<<<64, 256, 0, stream>>>(hh, ow, ob, ctx, scal, (float*)d_out);
}

// Round 15
// 522.914 us; speedup vs baseline: 1.0606x; 1.0606x over previous
//
#include <hip/hip_runtime.h>
#include <hip/hip_bf16.h>

#define NN   8192
#define NE   262144
#define HD   256
#define NHH  8194   // hh rows = N + 2

using f32x4  = __attribute__((ext_vector_type(4))) float;
using bf16x8 = __attribute__((ext_vector_type(8))) short;
typedef unsigned short u16;

#define GAS(p) ((const __attribute__((address_space(1))) void*)(p))
#define LAS(p) ((__attribute__((address_space(3))) void*)(p))

__device__ __forceinline__ u16 f2bf(float f) {
    unsigned u = __builtin_bit_cast(unsigned, f);
    u = (u + 0x7FFFu + ((u >> 16) & 1u)) >> 16;
    return (u16)u;
}
__device__ __forceinline__ float bf2f(u16 h) {
    return __builtin_bit_cast(float, (unsigned)h << 16);
}
__device__ __forceinline__ void split1(float a, u16& h, u16& l) {
    h = f2bf(a);
    l = f2bf(a - bf2f(h));   // a - hi is exact in fp32
}
__device__ __forceinline__ void store_split4(u16* hi, u16* lo, size_t off, float4 v) {
    ushort4 h, l;
    split1(v.x, h.x, l.x); split1(v.y, h.y, l.y);
    split1(v.z, h.z, l.z); split1(v.w, h.w, l.w);
    *(ushort4*)(hi + off) = h;
    *(ushort4*)(lo + off) = l;
}
__device__ __forceinline__ void add4(float4& a, float4 b) {
    a.x += b.x; a.y += b.y; a.z += b.z; a.w += b.w;
}

// ---------------------------------------------------------------- CSR build
__global__ void hist_kernel(const int* __restrict__ dst, int* __restrict__ cnt, int E) {
    int e = blockIdx.x * blockDim.x + threadIdx.x;
    if (e < E) atomicAdd(&cnt[dst[e]], 1);
}

__global__ __launch_bounds__(1024) void scan_kernel(const int* __restrict__ cnt, int* __restrict__ row_ptr) {
    __shared__ int sdata[1024];
    int tid = threadIdx.x;
    int v[8], local[8];
    int s = 0;
#pragma unroll
    for (int i = 0; i < 8; i++) v[i] = cnt[tid * 8 + i];
#pragma unroll
    for (int i = 0; i < 8; i++) { local[i] = s; s += v[i]; }
    sdata[tid] = s;
    __syncthreads();
    for (int off = 1; off < 1024; off <<= 1) {
        int t = (tid >= off) ? sdata[tid - off] : 0;
        __syncthreads();
        sdata[tid] += t;
        __syncthreads();
    }
    int base = (tid == 0) ? 0 : sdata[tid - 1];
#pragma unroll
    for (int i = 0; i < 8; i++) row_ptr[tid * 8 + i] = base + local[i];
    if (tid == 1023) row_ptr[8192] = sdata[1023];
}

__global__ void copy_int_kernel(const int* __restrict__ a, int* __restrict__ b, int n) {
    int i = blockIdx.x * blockDim.x + threadIdx.x;
    if (i < n) b[i] = a[i];
}

__global__ void fill_kernel(const int* __restrict__ dst, const int* __restrict__ src,
                            int* __restrict__ cursor, int* __restrict__ eids,
                            int* __restrict__ gsrc, int E) {
    int e = blockIdx.x * blockDim.x + threadIdx.x;
    if (e < E) {
        int pos = atomicAdd(&cursor[dst[e]], 1);
        eids[pos] = e;
        gsrc[pos] = src[e];
    }
}

// ---------------------------------------------- fused fp32 -> bf16x2 splits
struct SplitArgs {
    const float* src[11];
    u16* hi[11];
    u16* lo[11];
    int  off[12];
};
__global__ __launch_bounds__(256) void multisplit_kernel(SplitArgs a) {
    int blk = blockIdx.x;
    int s = 0;
#pragma unroll
    for (int t = 0; t < 11; ++t) if (blk >= a.off[t + 1]) s = t + 1;
    size_t i = ((size_t)(blk - a.off[s]) * 256 + threadIdx.x) * 4;
    float4 v = *(const float4*)(a.src[s] + i);
    store_split4(a.hi[s], a.lo[s], i, v);
}

// transpose + split: out[c][r] planes from W[r][c]
__global__ void wtrans_split_kernel(const float* __restrict__ W, u16* __restrict__ outh,
                                    u16* __restrict__ outl, int R, int Cc) {
    int j = blockIdx.x * 256 + threadIdx.x;
    if (j >= R * Cc) return;
    int r = j % R, c = j / R;
    u16 h, l;
    split1(W[(size_t)r * Cc + c], h, l);
    outh[j] = h; outl[j] = l;
}

// ------------------- L2-blocked wave-per-node segment sums (128-feat halves)
// 2 edge slots x 4-deep (needs only >=8 edges/slot for the pipelined loop).
struct SegDuo {
    const float* T0; u16* oh0; u16* ol0; int self0;
    const float* T1; u16* oh1; u16* ol1; int self1; int nb0;
};
__global__ __launch_bounds__(256) void segsum128_wave_kernel(const int* __restrict__ row_ptr,
                                                             const int* __restrict__ idx,
                                                             SegDuo a) {
    int blk  = blockIdx.x;
    int seg  = blk / a.nb0;              // 0..3
    int lblk = blk - seg * a.nb0;
    const float* T; u16* oh; u16* ol; int self;
    if (seg >> 1) { T = a.T1; oh = a.oh1; ol = a.ol1; self = a.self1; }
    else          { T = a.T0; oh = a.oh0; ol = a.ol0; self = a.self0; }
    const int half = seg & 1;
    const int n    = lblk * 4 + (threadIdx.x >> 6);
    const int lane = threadIdx.x & 63;
    const int slot = lane >> 5;          // 0/1
    const size_t fo = (size_t)half * 128 + (size_t)(lane & 31) * 4;
    const int b = row_ptr[n], e = row_ptr[n + 1];
    float4 z4 = make_float4(0.f, 0.f, 0.f, 0.f);
    float4 a0 = z4, a1 = z4, a2 = z4, a3 = z4;
    int i = b + slot;
    for (; i + 6 < e; i += 8) {          // this slot: edges i, i+2, i+4, i+6
        int s0 = idx[i], s1 = idx[i + 2], s2 = idx[i + 4], s3 = idx[i + 6];
        add4(a0, *(const float4*)(T + (size_t)s0 * HD + fo));
        add4(a1, *(const float4*)(T + (size_t)s1 * HD + fo));
        add4(a2, *(const float4*)(T + (size_t)s2 * HD + fo));
        add4(a3, *(const float4*)(T + (size_t)s3 * HD + fo));
    }
    for (; i < e; i += 2) {
        int s0 = idx[i];
        add4(a0, *(const float4*)(T + (size_t)s0 * HD + fo));
    }
    if (self && slot == 0) add4(a1, *(const float4*)(T + (size_t)n * HD + fo));
    add4(a0, a1); add4(a2, a3); add4(a0, a2);
    a0.x += __shfl_xor(a0.x, 32); a0.y += __shfl_xor(a0.y, 32);
    a0.z += __shfl_xor(a0.z, 32); a0.w += __shfl_xor(a0.w, 32);
    if (slot == 0) store_split4(oh, ol, (size_t)n * HD + fo, a0);
}

// 64-feat: wave per node, 4 edge-groups of 16 lanes, shfl_xor reduce.
__global__ __launch_bounds__(256) void segsum64_wave_kernel(const int* __restrict__ row_ptr,
                                                            const int* __restrict__ idx,
                                                            const float* __restrict__ T,
                                                            u16* __restrict__ outh,
                                                            u16* __restrict__ outl) {
    const int n    = blockIdx.x * 4 + (threadIdx.x >> 6);
    const int lane = threadIdx.x & 63;
    const int g    = lane >> 4;
    const size_t fo = (size_t)(lane & 15) * 4;
    const int b = row_ptr[n], e = row_ptr[n + 1];
    float4 a0 = make_float4(0.f, 0.f, 0.f, 0.f);
    float4 a1 = a0;
    int i = b + g;
    for (; i + 4 < e; i += 8) {
        int s0 = idx[i], s1 = idx[i + 4];
        add4(a0, *(const float4*)(T + (size_t)s0 * 64 + fo));
        add4(a1, *(const float4*)(T + (size_t)s1 * 64 + fo));
    }
    if (i < e) {
        int s0 = idx[i];
        add4(a0, *(const float4*)(T + (size_t)s0 * 64 + fo));
    }
    add4(a0, a1);
    a0.x += __shfl_xor(a0.x, 16); a0.y += __shfl_xor(a0.y, 16);
    a0.z += __shfl_xor(a0.z, 16); a0.w += __shfl_xor(a0.w, 16);
    a0.x += __shfl_xor(a0.x, 32); a0.y += __shfl_xor(a0.y, 32);
    a0.z += __shfl_xor(a0.z, 32); a0.w += __shfl_xor(a0.w, 32);
    if (g == 0) store_split4(outh, outl, (size_t)n * 64 + fo, a0);
}

// ---------------- batched LDS-staged split-bf16 3-product MFMA GEMM
// 128x64 C-tile, 4 waves of 64x32. BK=64. LDS stride 64 u16 + XOR swizzle.
// Staging via global_load_lds width=16 with pre-swizzled global source (m173).
// flags: 1 = relu, 2 = accumulate into C (skip bias)
struct GDesc {
    const u16 *Ah, *Al, *Abh, *Abl, *Wh, *Wl;
    const float* bias;
    float* C; u16 *Chi, *Clo;
    int lda, ldab, Ka, Kb, ldw, ldc, M, flags, nbx, nblk;
};
struct GBatch { GDesc d[3]; int start[4]; };

#define LDSA0 0
#define LDSA1 8192
#define LDSW0 16384
#define LDSW1 20480
__global__ __launch_bounds__(256) void hgemm_kernel(GBatch b) {
    __shared__ __align__(16) u16 lds[24576];
    int s = (blockIdx.x >= (unsigned)b.start[1]) + (blockIdx.x >= (unsigned)b.start[2]);
    GDesc d = b.d[0];
    if (s == 1) d = b.d[1];
    else if (s == 2) d = b.d[2];

    // local bijective XCD swizzle within this desc's block range
    int nwg = b.start[s + 1] - b.start[s];
    int o   = blockIdx.x - b.start[s];
    int q = nwg >> 3, r = nwg & 7;
    int xcd = o & 7;
    int base = (xcd < r) ? xcd * (q + 1) : r * (q + 1) + (xcd - r) * q;
    int wg = base + (o >> 3);
    int bx = wg % d.nbx, by = wg / d.nbx;

    const int tid  = threadIdx.x;
    const int wid  = tid >> 6;
    const int lane = tid & 63;
    const int lrow = lane & 15;
    const int ksel = lane >> 4;
    const int rswz = (lrow & 7) << 3;

    // gload_lds staging geometry: chunk j = i*256 + tid; row=j>>3; c_dst=lane&7
    const int arow_l = wid * 8 + (lane >> 3);            // + i*32 per issue
    const int csrc8  = ((lane & 7) ^ ((lane >> 3) & 7)) * 8;  // u16 offset of source chunk

    const int nt = (d.Ka + d.Kb) >> 6;

    auto stage = [&](int t) {
        int kb = t << 6;
        const u16 *ph, *pl; int ld_; int kk;
        if (kb < d.Ka) { ph = d.Ah;  pl = d.Al;  ld_ = d.lda;  kk = kb; }
        else           { ph = d.Abh; pl = d.Abl; ld_ = d.ldab; kk = kb - d.Ka; }
#pragma unroll
        for (int i = 0; i < 4; ++i) {
            int row = i * 32 + arow_l;
            int rg  = min(by * 128 + row, d.M - 1);
            const u16* gah = ph + (size_t)rg * ld_ + kk + csrc8;
            const u16* gal = pl + (size_t)rg * ld_ + kk + csrc8;
            char* ba = (char*)lds + i * 4096 + wid * 1024;
            __builtin_amdgcn_global_load_lds(GAS(gah), LAS(ba), 16, 0, 0);
            __builtin_amdgcn_global_load_lds(GAS(gal), LAS(ba + LDSA1 * 2), 16, 0, 0);
        }
#pragma unroll
        for (int i = 0; i < 2; ++i) {
            int row = i * 32 + arow_l;
            size_t wo = (size_t)(bx * 64 + row) * d.ldw + kb + csrc8;
            const u16* gwh = d.Wh + wo;
            const u16* gwl = d.Wl + wo;
            char* bw = (char*)lds + LDSW0 * 2 + i * 4096 + wid * 1024;
            __builtin_amdgcn_global_load_lds(GAS(gwh), LAS(bw), 16, 0, 0);
            __builtin_amdgcn_global_load_lds(GAS(gwl), LAS(bw + (LDSW1 - LDSW0) * 2), 16, 0, 0);
        }
    };

    f32x4 acc[4][2] = {};
    const int fr0 = (wid >> 1) * 64;
    const int cr0 = (wid & 1) * 32;

    for (int t = 0; t < nt; ++t) {
        stage(t);
        __syncthreads();          // drains vmcnt -> LDS tile ready
#pragma unroll
        for (int ks = 0; ks < 2; ++ks) {
            bf16x8 fah[4], fal[4], fwh[2], fwl[2];
            const int ko = (ks * 32 + ksel * 8) ^ rswz;
#pragma unroll
            for (int fi = 0; fi < 4; ++fi) {
                int oo = (fr0 + fi * 16 + lrow) * 64 + ko;
                fah[fi] = *(const bf16x8*)(lds + LDSA0 + oo);
                fal[fi] = *(const bf16x8*)(lds + LDSA1 + oo);
            }
#pragma unroll
            for (int ci = 0; ci < 2; ++ci) {
                int oo = (cr0 + ci * 16 + lrow) * 64 + ko;
                fwh[ci] = *(const bf16x8*)(lds + LDSW0 + oo);
                fwl[ci] = *(const bf16x8*)(lds + LDSW1 + oo);
            }
#pragma unroll
            for (int fi = 0; fi < 4; ++fi)
#pragma unroll
                for (int ci = 0; ci < 2; ++ci) {
                    acc[fi][ci] = __builtin_amdgcn_mfma_f32_16x16x32_bf16(fah[fi], fwh[ci], acc[fi][ci], 0, 0, 0);
                    acc[fi][ci] = __builtin_amdgcn_mfma_f32_16x16x32_bf16(fah[fi], fwl[ci], acc[fi][ci], 0, 0, 0);
                    acc[fi][ci] = __builtin_amdgcn_mfma_f32_16x16x32_bf16(fal[fi], fwh[ci], acc[fi][ci], 0, 0, 0);
                }
        }
        __syncthreads();          // all reads done before next stage overwrites
    }

#pragma unroll
    for (int fi = 0; fi < 4; ++fi) {
        int rbase = by * 128 + fr0 + fi * 16 + (lane >> 4) * 4;
#pragma unroll
        for (int ci = 0; ci < 2; ++ci) {
            int col = bx * 64 + cr0 + ci * 16 + lrow;
#pragma unroll
            for (int j = 0; j < 4; ++j) {
                int rr = rbase + j;
                if (rr >= d.M) continue;
                float v = acc[fi][ci][j];
                size_t oo = (size_t)rr * d.ldc + col;
                if (d.flags & 2)    v += d.C[oo];
                else if (d.bias)    v += d.bias[col];
                if (d.flags & 1)    v = fmaxf(v, 0.f);
                if (d.C) d.C[oo] = v;
                if (d.Chi) { u16 hb, lb; split1(v, hb, lb); d.Chi[oo] = hb; d.Clo[oo] = lb; }
            }
        }
    }
}

// ----------------------------------------------------------- GRU elementwise
__global__ void gru_combine_kernel(const float* __restrict__ gi, const float* __restrict__ gh,
                                   const float* __restrict__ hprev, float* __restrict__ hout,
                                   u16* __restrict__ hhi, u16* __restrict__ hlo, int total4) {
    int t = blockIdx.x * 256 + threadIdx.x;
    if (t >= total4) return;
    int i4  = t * 4;
    int row = i4 >> 8, f = i4 & 255;
    size_t b = (size_t)row * 768;
    float4 ir = *(const float4*)(gi + b + f);
    float4 iz = *(const float4*)(gi + b + 256 + f);
    float4 in_ = *(const float4*)(gi + b + 512 + f);
    float4 hr = *(const float4*)(gh + b + f);
    float4 hz = *(const float4*)(gh + b + 256 + f);
    float4 hn = *(const float4*)(gh + b + 512 + f);
    float4 hp = *(const float4*)(hprev + (size_t)row * HD + f);
    float4 hv;
#pragma unroll
    for (int j = 0; j < 4; ++j) {
        float irj = ((const float*)&ir)[j], izj = ((const float*)&iz)[j], inj = ((const float*)&in_)[j];
        float hrj = ((const float*)&hr)[j], hzj = ((const float*)&hz)[j], hnj = ((const float*)&hn)[j];
        float r = 1.f / (1.f + expf(-(irj + hrj)));
        float z = 1.f / (1.f + expf(-(izj + hzj)));
        float n = tanhf(inj + r * hnj);
        ((float*)&hv)[j] = (1.f - z) * n + z * ((const float*)&hp)[j];
    }
    size_t o = (size_t)row * HD + f;
    *(float4*)(hout + o) = hv;
    if (hhi) store_split4(hhi, hlo, o, hv);
}

// ------------------------------------------------------------------ epilogue
__global__ void hhtail_kernel(const float* __restrict__ rc, const float* __restrict__ si,
                              float* __restrict__ hh, u16* __restrict__ hhi, u16* __restrict__ hlo) {
    int f = threadIdx.x;
    size_t o1 = (size_t)NN * HD + f, o2 = (size_t)(NN + 1) * HD + f;
    float a = rc[f], b = si[f];
    hh[o1] = a; hh[o2] = b;
    u16 h, l;
    split1(a, h, l); hhi[o1] = h; hlo[o1] = l;
    split1(b, h, l); hhi[o2] = h; hlo[o2] = l;
}

__global__ __launch_bounds__(256) void alpha_kernel(const float* __restrict__ g1, const float* __restrict__ gw2,
                                                    const float* __restrict__ gb2, const int* __restrict__ rcmask,
                                                    float* __restrict__ coef, int N) {
    int node = blockIdx.x * 4 + (threadIdx.x >> 6);
    int lane = threadIdx.x & 63;
    if (node >= N) return;
    float part = g1[(size_t)node * 128 + lane] * gw2[lane]
               + g1[(size_t)node * 128 + 64 + lane] * gw2[64 + lane];
    for (int off = 32; off > 0; off >>= 1) part += __shfl_down(part, off);
    if (lane == 0) {
        float a = 1.f / (1.f + expf(-(part + gb2[0])));
        coef[node] = rcmask[node] ? 0.f : a;
    }
}

__global__ __launch_bounds__(256) void colsum_kernel(const float* __restrict__ X, const float* __restrict__ coef,
                                                     float* __restrict__ out, int rows_total, int rows_per_blk) {
    int f  = threadIdx.x;
    int r0 = blockIdx.x * rows_per_blk;
    int r1 = r0 + rows_per_blk; if (r1 > rows_total) r1 = rows_total;
    float a0 = 0.f, a1 = 0.f;
    int r = r0;
    for (; r + 1 < r1; r += 2) {
        a0 += coef[r]     * X[(size_t)r * HD + f];
        a1 += coef[r + 1] * X[(size_t)(r + 1) * HD + f];
    }
    if (r < r1) a0 += coef[r] * X[(size_t)r * HD + f];
    atomicAdd(&out[f], a0 + a1);
}

__global__ __launch_bounds__(256) void gemv256_kernel(const float* __restrict__ M,
                                                      const float* __restrict__ vA,
                                                      const float* __restrict__ vB,
                                                      const float* __restrict__ bias,
                                                      float* __restrict__ out, int R) {
    int row  = blockIdx.x * 4 + (threadIdx.x >> 6);
    int lane = threadIdx.x & 63;
    if (row >= R) return;
    float4 v = *(const float4*)(vA + lane * 4);
    if (vB) {
        float4 b = *(const float4*)(vB + lane * 4);
        v.x += b.x; v.y += b.y; v.z += b.z; v.w += b.w;
    }
    float4 m = *(const float4*)(M + (size_t)row * 256 + lane * 4);
    float p = m.x * v.x + m.y * v.y + m.z * v.z + m.w * v.w;
    for (int off = 32; off > 0; off >>= 1) p += __shfl_down(p, off);
    if (lane == 0) out[row] = p + (bias ? bias[row] : 0.f);
}

__global__ void sgru_combine_kernel(const float* __restrict__ gi3, const float* __restrict__ gh3,
                                    const float* __restrict__ sinit,
                                    float* __restrict__ hh, u16* __restrict__ hhi, u16* __restrict__ hlo) {
    int f = threadIdx.x;
    float gir = gi3[f], giz = gi3[256 + f], gin_ = gi3[512 + f];
    float ghr = gh3[f], ghz = gh3[256 + f], ghn  = gh3[512 + f];
    float r = 1.f / (1.f + expf(-(gir + ghr)));
    float z = 1.f / (1.f + expf(-(giz + ghz)));
    float n = tanhf(gin_ + r * ghn);
    float hv = (1.f - z) * n + z * sinit[f];
    size_t o = (size_t)(NN + 1) * HD + f;
    hh[o] = hv;
    u16 h, l; split1(hv, h, l); hhi[o] = h; hlo[o] = l;
}

__global__ __launch_bounds__(256) void logits_kernel(const float* __restrict__ kall, const float* __restrict__ qrow,
                                                     float* __restrict__ logits, int n) {
    int j    = blockIdx.x * 4 + (threadIdx.x >> 6);
    int lane = threadIdx.x & 63;
    if (j >= n) return;
    float4 q = *(const float4*)(qrow + lane * 4);
    float4 k = *(const float4*)(kall + (size_t)j * HD + lane * 4);
    float part = q.x * k.x + q.y * k.y + q.z * k.z + q.w * k.w;
    for (int off = 32; off > 0; off >>= 1) part += __shfl_down(part, off);
    if (lane == 0) logits[j] = part * 0.0625f;
}

__global__ __launch_bounds__(1024) void softmax_prep_kernel(const float* __restrict__ logits, float* __restrict__ p,
                                                            float* __restrict__ scal, int n) {
    __shared__ float sd[1024];
    int tid = threadIdx.x;
    float mx = -1e30f;
    for (int j = tid; j < n; j += 1024) mx = fmaxf(mx, logits[j]);
    sd[tid] = mx;
    __syncthreads();
    for (int off = 512; off > 0; off >>= 1) { if (tid < off) sd[tid] = fmaxf(sd[tid], sd[tid + off]); __syncthreads(); }
    float m = sd[0];
    __syncthreads();
    float s = 0.f;
    for (int j = tid; j < n; j += 1024) { float e = expf(logits[j] - m); p[j] = e; s += e; }
    sd[tid] = s;
    __syncthreads();
    for (int off = 512; off > 0; off >>= 1) { if (tid < off) sd[tid] += sd[tid + off]; __syncthreads(); }
    if (tid == 0) scal[0] = sd[0];
}

__global__ __launch_bounds__(256) void final_gemv_kernel(const float* __restrict__ hh,
                                                         const float* __restrict__ ow,
                                                         const float* __restrict__ ob,
                                                         const float* __restrict__ ctx,
                                                         const float* __restrict__ scal,
                                                         float* __restrict__ out) {
    int row  = blockIdx.x * 4 + (threadIdx.x >> 6);
    int lane = threadIdx.x & 63;
    float4 c = *(const float4*)(ctx + lane * 4);
    float4 m = *(const float4*)(ow + (size_t)row * 256 + lane * 4);
    float p = m.x * c.x + m.y * c.y + m.z * c.z + m.w * c.w;
    for (int off = 32; off > 0; off >>= 1) p += __shfl_down(p, off);
    if (lane == 0) {
        float val = hh[(size_t)(NN + 1) * HD + row] + p / scal[0] + ob[row];
        out[row] = fmaxf(val, 0.f);
    }
}

// ---------------------------------------------------------------------------
extern "C" void kernel_launch(void* const* d_in, const int* in_sizes, int n_in,
                              void* d_out, int out_size, void* d_ws, size_t ws_size,
                              hipStream_t stream) {
    const float* x      = (const float*)d_in[0];
    const int*   ei     = (const int*)  d_in[1];
    const float* eattr  = (const float*)d_in[2];
    const int*   rcmask = (const int*)  d_in[3];
    const float* Wmsg1  = (const float*)d_in[4];
    const float* wih1   = (const float*)d_in[5];
    const float* whh1   = (const float*)d_in[6];
    const float* bih1   = (const float*)d_in[7];
    const float* bhh1   = (const float*)d_in[8];
    const float* Wmsg2  = (const float*)d_in[9];
    const float* wih2   = (const float*)d_in[10];
    const float* whh2   = (const float*)d_in[11];
    const float* bih2   = (const float*)d_in[12];
    const float* bhh2   = (const float*)d_in[13];
    const float* ginw1  = (const float*)d_in[14];
    const float* ginb1  = (const float*)d_in[15];
    const float* ginw2  = (const float*)d_in[16];
    const float* ginb2  = (const float*)d_in[17];
    const float* projw  = (const float*)d_in[18];
    const float* projb  = (const float*)d_in[19];
    const float* qw     = (const float*)d_in[20];
    const float* qb     = (const float*)d_in[21];
    const float* kw     = (const float*)d_in[22];
    const float* kb     = (const float*)d_in[23];
    const float* vw     = (const float*)d_in[24];
    const float* vb     = (const float*)d_in[25];
    const float* ow     = (const float*)d_in[26];
    const float* ob     = (const float*)d_in[27];
    const float* gatew1 = (const float*)d_in[28];
    const float* gateb1 = (const float*)d_in[29];
    const float* gatew2 = (const float*)d_in[30];
    const float* gateb2 = (const float*)d_in[31];
    const float* skipW  = (const float*)d_in[32];
    const float* swih   = (const float*)d_in[33];
    const float* swhh   = (const float*)d_in[34];
    const float* sbih   = (const float*)d_in[35];
    const float* sbhh   = (const float*)d_in[36];
    const float* rcinit = (const float*)d_in[37];
    const float* sinit  = (const float*)d_in[38];

    const int* src = ei;
    const int* dst = ei + NE;

    // ---------------- workspace layout -------------------------------------
    char*  w   = (char*)d_ws;
    size_t off = 0;
    auto alloc = [&](size_t bytes) -> void* {
        void* p = w + off;
        off = (off + bytes + 255) & ~(size_t)255;
        return p;
    };
    int*   cnt     = (int*)alloc((size_t)NN * 4);
    int*   row_ptr = (int*)alloc((size_t)(NN + 1) * 4);
    int*   eids    = (int*)alloc((size_t)NE * 4);
    int*   gsrc    = (int*)alloc((size_t)NE * 4);
    u16*   aeh     = (u16*)alloc((size_t)NN * 64 * 2);
    u16*   ael     = (u16*)alloc((size_t)NN * 64 * 2);
    u16*   shh_    = (u16*)alloc((size_t)NHH * HD * 2);    // x / hh planes
    u16*   shl_    = (u16*)alloc((size_t)NHH * HD * 2);
    u16*   gsh     = (u16*)alloc((size_t)NN * HD * 2);
    u16*   gsl     = (u16*)alloc((size_t)NN * HD * 2);
    u16*   gs2h    = (u16*)alloc((size_t)NN * HD * 2);
    u16*   gs2l    = (u16*)alloc((size_t)NN * HD * 2);
    u16*   msh     = (u16*)alloc((size_t)NN * HD * 2);
    u16*   msl     = (u16*)alloc((size_t)NN * HD * 2);
    u16*   ms2h    = (u16*)alloc((size_t)NN * HD * 2);
    u16*   ms2l    = (u16*)alloc((size_t)NN * HD * 2);
    float* h1      = (float*)alloc((size_t)NN * HD * 4);
    float* h2      = (float*)alloc((size_t)NN * HD * 4);
    float* gi      = (float*)alloc((size_t)NN * 768 * 4);  // gi fp32
    float* gh      = (float*)alloc((size_t)NN * 768 * 4);  // gh fp32; u768 planes / scratch / k,v
    float* hh      = (float*)alloc((size_t)NHH * HD * 4);
    float* coef    = (float*)alloc((size_t)NN * 4);
    float* wsum    = (float*)alloc(256 * 4);
    float* qrow    = (float*)alloc(256 * 4);
    float* logits  = (float*)alloc((size_t)NHH * 4);
    float* pbuf    = (float*)alloc((size_t)NHH * 4);
    float* scal    = (float*)alloc(256);
    float* ctx     = (float*)alloc(256 * 4);
    float* mvec    = (float*)alloc(256 * 4);
    float* gi3     = (float*)alloc(768 * 4);
    float* gh3     = (float*)alloc(768 * 4);

    auto walloc = [&](size_t nel, u16** h, u16** l) {
        *h = (u16*)alloc(nel * 2); *l = (u16*)alloc(nel * 2);
    };
    u16 *wm1Th, *wm1Tl, *wm2Th, *wm2Tl;
    u16 *wc1h, *wc1l, *wc2h, *wc2l;
    u16 *wi1h, *wi1l, *wh1h, *wh1l, *wi2h, *wi2l, *wh2h, *wh2l;
    u16 *g1h, *g1l, *g2h, *g2l, *pjh, *pjl, *gwh, *gwl, *kwh, *kwl, *vwh, *vwl;
    walloc(81920, &wm1Th, &wm1Tl); walloc(81920, &wm2Th, &wm2Tl);
    walloc(245760, &wc1h, &wc1l);  walloc(245760, &wc2h, &wc2l);
    walloc(196608, &wi1h, &wi1l);  walloc(196608, &wh1h, &wh1l);
    walloc(196608, &wi2h, &wi2l);  walloc(196608, &wh2h, &wh2l);
    walloc(196608, &g1h, &g1l);    walloc(196608, &g2h, &g2l);
    walloc(196608, &pjh, &pjl);    walloc(32768, &gwh, &gwl);
    walloc(65536, &kwh, &kwl);     walloc(65536, &vwh, &vwl);
    u16 *xh = shh_, *xl = shl_;

    // phase aliases (gh region: fp32 in DMPNN; u768 planes then scratch in GIN; k/v late)
    u16*   u768h = (u16*)gh;
    u16*   u768l = u768h + (size_t)NN * 768;
    u16*   sAh   = (u16*)gh;                       // scratch planes after u768 dead
    u16*   sAl   = sAh + (size_t)NN * HD;
    u16*   sBh   = sAh + (size_t)2 * NN * HD;
    u16*   sBl   = sAh + (size_t)3 * NN * HD;
    float* k_all = gh;
    float* v_all = gh + (size_t)NHH * HD;
    float* g1    = gh + (size_t)2 * NHH * HD;

    auto mkd = [&](const u16* Ah, const u16* Al, int lda,
                   const u16* Abh, const u16* Abl, int ldab, int Ka, int Kb,
                   const u16* Wh, const u16* Wl, int ldw, const float* bias,
                   float* C, u16* Chi, u16* Clo, int ldc,
                   int M, int Nc, int flags) -> GDesc {
        GDesc d;
        d.Ah = Ah; d.Al = Al; d.Abh = Abh; d.Abl = Abl; d.Wh = Wh; d.Wl = Wl;
        d.bias = bias; d.C = C; d.Chi = Chi; d.Clo = Clo;
        d.lda = lda; d.ldab = ldab; d.Ka = Ka; d.Kb = Kb; d.ldw = ldw; d.ldc = ldc;
        d.M = M; d.flags = flags; d.nbx = Nc / 64;
        d.nblk = d.nbx * ((M + 127) / 128);
        return d;
    };
    auto hg1 = [&](GDesc d0) {
        GBatch b; b.d[0] = d0; b.d[1] = d0; b.d[2] = d0;
        b.start[0] = 0; b.start[1] = d0.nblk; b.start[2] = d0.nblk; b.start[3] = d0.nblk;
        hgemm_kernel<<<b.start[3], 256, 0, stream>>>(b);
    };
    auto hg2 = [&](GDesc d0, GDesc d1) {
        GBatch b; b.d[0] = d0; b.d[1] = d1; b.d[2] = d1;
        b.start[0] = 0; b.start[1] = d0.nblk; b.start[2] = d0.nblk + d1.nblk; b.start[3] = b.start[2];
        hgemm_kernel<<<b.start[3], 256, 0, stream>>>(b);
    };
    auto hg3 = [&](GDesc d0, GDesc d1, GDesc d2) {
        GBatch b; b.d[0] = d0; b.d[1] = d1; b.d[2] = d2;
        b.start[0] = 0; b.start[1] = d0.nblk; b.start[2] = d0.nblk + d1.nblk;
        b.start[3] = b.start[2] + d2.nblk;
        hgemm_kernel<<<b.start[3], 256, 0, stream>>>(b);
    };
    auto seg1 = [&](const float* T, u16* oh, u16* ol, int self) {
        SegDuo a; a.T0 = T; a.oh0 = oh; a.ol0 = ol; a.self0 = self;
        a.T1 = T; a.oh1 = oh; a.ol1 = ol; a.self1 = self; a.nb0 = NN / 4;
        segsum128_wave_kernel<<<2 * (NN / 4), 256, 0, stream>>>(row_ptr, gsrc, a);
    };
    auto seg2 = [&](const float* T0, u16* oh0, u16* ol0, int s0,
                    const float* T1, u16* oh1, u16* ol1, int s1) {
        SegDuo a; a.T0 = T0; a.oh0 = oh0; a.ol0 = ol0; a.self0 = s0;
        a.T1 = T1; a.oh1 = oh1; a.ol1 = ol1; a.self1 = s1; a.nb0 = NN / 4;
        segsum128_wave_kernel<<<4 * (NN / 4), 256, 0, stream>>>(row_ptr, gsrc, a);
    };

    // ------------------------------ CSR build ------------------------------
    hipMemsetAsync(cnt, 0, (size_t)NN * 4, stream);
    hist_kernel<<<NE / 256, 256, 0, stream>>>(dst, cnt, NE);
    scan_kernel<<<1, 1024, 0, stream>>>(cnt, row_ptr);
    copy_int_kernel<<<NN / 256, 256, 0, stream>>>(row_ptr, cnt, NN);
    fill_kernel<<<NE / 256, 256, 0, stream>>>(dst, src, cnt, eids, gsrc, NE);
    segsum64_wave_kernel<<<NN / 4, 256, 0, stream>>>(row_ptr, eids, eattr, aeh, ael);

    // ------------------------------ one-time splits ------------------------
    {
        SplitArgs a;
        const float* srcs[11] = { x, wih1, whh1, wih2, whh2,
                                  ginw1, ginw2, projw, gatew1, kw, vw };
        u16* his[11] = { xh, wi1h, wh1h, wi2h, wh2h, g1h, g2h, pjh, gwh, kwh, vwh };
        u16* los[11] = { xl, wi1l, wh1l, wi2l, wh2l, g1l, g2l, pjl, gwl, kwl, vwl };
        const int blocks[11] = { 2048, 192, 192, 192, 192, 192, 192, 192, 32, 64, 64 };
        int acc = 0;
        for (int t = 0; t < 11; ++t) { a.src[t] = srcs[t]; a.hi[t] = his[t]; a.lo[t] = los[t]; a.off[t] = acc; acc += blocks[t]; }
        a.off[11] = acc;
        multisplit_kernel<<<acc, 256, 0, stream>>>(a);
    }
    wtrans_split_kernel<<<(81920 + 255) / 256, 256, 0, stream>>>(Wmsg1, wm1Th, wm1Tl, 256, 320);
    wtrans_split_kernel<<<(81920 + 255) / 256, 256, 0, stream>>>(Wmsg2, wm2Th, wm2Tl, 256, 320);
    // Wc = wih @ Wmsg   ([768][320] planes), both layers in one dispatch
    hg2(mkd(wi1h, wi1l, HD, nullptr, nullptr, 0, HD, 0, wm1Th, wm1Tl, HD, nullptr,
            nullptr, wc1h, wc1l, 320, 768, 320, 0),
        mkd(wi2h, wi2l, HD, nullptr, nullptr, 0, HD, 0, wm2Th, wm2Tl, HD, nullptr,
            nullptr, wc2h, wc2l, 320, 768, 320, 0));

    // ------------------------------ DMPNN 1 --------------------------------
    seg1(x, gsh, gsl, 0);
    hg2(mkd(gsh, gsl, HD, aeh, ael, 64, HD, 64, wc1h, wc1l, 320, bih1,
            gi, nullptr, nullptr, 768, NN, 768, 0),
        mkd(shh_, shl_, HD, nullptr, nullptr, 0, HD, 0, wh1h, wh1l, HD, bhh1,
            gh, nullptr, nullptr, 768, NN, 768, 0));
    gru_combine_kernel<<<NN * HD / 1024, 256, 0, stream>>>(gi, gh, x, h1, gs2h, gs2l, NN * HD / 4);

    // ------------------------------ DMPNN 2 --------------------------------
    seg1(h1, gsh, gsl, 0);
    hg2(mkd(gsh, gsl, HD, aeh, ael, 64, HD, 64, wc2h, wc2l, 320, bih2,
            gi, nullptr, nullptr, 768, NN, 768, 0),
        mkd(gs2h, gs2l, HD, nullptr, nullptr, 0, HD, 0, wh2h, wh2l, HD, bhh2,
            gh, nullptr, nullptr, 768, NN, 768, 0));
    gru_combine_kernel<<<NN * HD / 1024, 256, 0, stream>>>(gi, gh, h1, h2, nullptr, nullptr, NN * HD / 4);

    // ------------------------------ GIN towers (proj folded, batched) ------
    seg1(h2, gsh, gsl, 1);
    hg1(mkd(gsh, gsl, HD, nullptr, nullptr, 0, HD, 0, g1h, g1l, HD, ginb1,
            nullptr, u768h, u768l, 768, NN, 768, 1));
    hg3(mkd(u768h, u768l, 768, nullptr, nullptr, 0, HD, 0, g2h, g2l, HD, ginb2,
            nullptr, msh, msl, HD, NN, HD, 0),
        mkd(u768h + 256, u768l + 256, 768, nullptr, nullptr, 0, HD, 0, g2h + 65536, g2l + 65536, HD, ginb2 + 256,
            h1, nullptr, nullptr, HD, NN, HD, 0),
        mkd(u768h + 512, u768l + 512, 768, nullptr, nullptr, 0, HD, 0, g2h + 131072, g2l + 131072, HD, ginb2 + 512,
            h2, nullptr, nullptr, HD, NN, HD, 0));
    // towers 1,2 hop-2 aggregations (u768 now dead -> sA/sB scratch usable)
    seg2(h1, gsh, gsl, 1, h2, gs2h, gs2l, 1);
    // batch: proj slice 0 (reads msh) + g1 for towers 1,2 (write sA, sB)
    hg3(mkd(msh, msl, HD, nullptr, nullptr, 0, HD, 0, pjh, pjl, 768, projb,
            hh, nullptr, nullptr, HD, NN, HD, 0),
        mkd(gsh, gsl, HD, nullptr, nullptr, 0, HD, 0, g1h + 65536, g1l + 65536, HD, ginb1 + 256,
            nullptr, sAh, sAl, HD, NN, HD, 1),
        mkd(gs2h, gs2l, HD, nullptr, nullptr, 0, HD, 0, g1h + 131072, g1l + 131072, HD, ginb1 + 512,
            nullptr, sBh, sBl, HD, NN, HD, 1));
    // g2: tower1 final -> gsh planes, tower2 mid -> h1 fp32
    hg2(mkd(sAh, sAl, HD, nullptr, nullptr, 0, HD, 0, g2h + 65536, g2l + 65536, HD, ginb2 + 256,
            nullptr, gsh, gsl, HD, NN, HD, 0),
        mkd(sBh, sBl, HD, nullptr, nullptr, 0, HD, 0, g2h + 131072, g2l + 131072, HD, ginb2 + 512,
            h1, nullptr, nullptr, HD, NN, HD, 0));
    // tower2 hop-3 agg
    seg1(h1, gs2h, gs2l, 1);
    // batch: proj slice 1 (reads gsh, hh += ) + tower2 g1 (gs2 -> ms2)
    hg2(mkd(gsh, gsl, HD, nullptr, nullptr, 0, HD, 0, pjh + 256, pjl + 256, 768, nullptr,
            hh, nullptr, nullptr, HD, NN, HD, 2),
        mkd(gs2h, gs2l, HD, nullptr, nullptr, 0, HD, 0, g1h + 131072, g1l + 131072, HD, ginb1 + 512,
            nullptr, ms2h, ms2l, HD, NN, HD, 1));
    hg1(mkd(ms2h, ms2l, HD, nullptr, nullptr, 0, HD, 0, g2h + 131072, g2l + 131072, HD, ginb2 + 512,
            nullptr, gs2h, gs2l, HD, NN, HD, 0));
    // proj slice 2: hh += t2f @ projw[:, 512:768]^T ; emit hh planes
    hg1(mkd(gs2h, gs2l, HD, nullptr, nullptr, 0, HD, 0, pjh + 512, pjl + 512, 768, nullptr,
            hh, shh_, shl_, HD, NN, HD, 2));
    hhtail_kernel<<<1, 256, 0, stream>>>(rcinit, sinit, hh, shh_, shl_);

    // ------------------------------ gate / skip-sum / sGRU -----------------
    hg1(mkd(shh_, shl_, HD, nullptr, nullptr, 0, HD, 0, gwh, gwl, HD, gateb1,
            g1, nullptr, nullptr, 128, NN, 128, 1));
    alpha_kernel<<<NN / 4, 256, 0, stream>>>(g1, gatew2, gateb2, rcmask, coef, NN);
    hipMemsetAsync(wsum, 0, 256 * 4, stream);
    colsum_kernel<<<256, 256, 0, stream>>>(hh, coef, wsum, NN, 32);
    gemv256_kernel<<<64, 256, 0, stream>>>(skipW, wsum, rcinit, nullptr, mvec, 256);
    gemv256_kernel<<<192, 256, 0, stream>>>(swih, mvec, nullptr, sbih, gi3, 768);
    gemv256_kernel<<<192, 256, 0, stream>>>(swhh, sinit, nullptr, sbhh, gh3, 768);
    sgru_combine_kernel<<<1, 256, 0, stream>>>(gi3, gh3, sinit, hh, shh_, shl_);

    // ------------------------------ attention row --------------------------
    hg2(mkd(shh_, shl_, HD, nullptr, nullptr, 0, HD, 0, kwh, kwl, HD, kb,
            k_all, nullptr, nullptr, HD, NHH, HD, 0),
        mkd(shh_, shl_, HD, nullptr, nullptr, 0, HD, 0, vwh, vwl, HD, vb,
            v_all, nullptr, nullptr, HD, NHH, HD, 0));
    gemv256_kernel<<<64, 256, 0, stream>>>(qw, hh + (size_t)(NN + 1) * HD, nullptr, qb, qrow, 256);
    logits_kernel<<<(NHH + 3) / 4, 256, 0, stream>>>(k_all, qrow, logits, NHH);
    softmax_prep_kernel<<<1, 1024, 0, stream>>>(logits, pbuf, scal, NHH);
    hipMemsetAsync(ctx, 0, 256 * 4, stream);
    colsum_kernel<<<(NHH + 31) / 32, 256, 0, stream>>>(v_all, pbuf, ctx, NHH, 32);
    final_gemv_kernel<<<64, 256, 0, stream>>>(hh, ow, ob, ctx, scal, (float*)d_out);
}

// Round 16
// 513.691 us; speedup vs baseline: 1.0796x; 1.0180x over previous
//
#include <hip/hip_runtime.h>
#include <hip/hip_bf16.h>

#define NN   8192
#define NE   262144
#define HD   256
#define NHH  8194   // hh rows = N + 2

using f32x4  = __attribute__((ext_vector_type(4))) float;
using bf16x8 = __attribute__((ext_vector_type(8))) short;
typedef unsigned short u16;

#define GAS(p) ((const __attribute__((address_space(1))) void*)(p))
#define LAS(p) ((__attribute__((address_space(3))) void*)(p))

__device__ __forceinline__ u16 f2bf(float f) {
    unsigned u = __builtin_bit_cast(unsigned, f);
    u = (u + 0x7FFFu + ((u >> 16) & 1u)) >> 16;
    return (u16)u;
}
__device__ __forceinline__ float bf2f(u16 h) {
    return __builtin_bit_cast(float, (unsigned)h << 16);
}
__device__ __forceinline__ void split1(float a, u16& h, u16& l) {
    h = f2bf(a);
    l = f2bf(a - bf2f(h));   // a - hi is exact in fp32
}
__device__ __forceinline__ void store_split4(u16* hi, u16* lo, size_t off, float4 v) {
    ushort4 h, l;
    split1(v.x, h.x, l.x); split1(v.y, h.y, l.y);
    split1(v.z, h.z, l.z); split1(v.w, h.w, l.w);
    *(ushort4*)(hi + off) = h;
    *(ushort4*)(lo + off) = l;
}
__device__ __forceinline__ void add4(float4& a, float4 b) {
    a.x += b.x; a.y += b.y; a.z += b.z; a.w += b.w;
}

// ---------------------------------------------------------------- CSR build
__global__ void hist_kernel(const int* __restrict__ dst, int* __restrict__ cnt, int E) {
    int e = blockIdx.x * blockDim.x + threadIdx.x;
    if (e < E) atomicAdd(&cnt[dst[e]], 1);
}

__global__ __launch_bounds__(1024) void scan_kernel(const int* __restrict__ cnt, int* __restrict__ row_ptr) {
    __shared__ int sdata[1024];
    int tid = threadIdx.x;
    int v[8], local[8];
    int s = 0;
#pragma unroll
    for (int i = 0; i < 8; i++) v[i] = cnt[tid * 8 + i];
#pragma unroll
    for (int i = 0; i < 8; i++) { local[i] = s; s += v[i]; }
    sdata[tid] = s;
    __syncthreads();
    for (int off = 1; off < 1024; off <<= 1) {
        int t = (tid >= off) ? sdata[tid - off] : 0;
        __syncthreads();
        sdata[tid] += t;
        __syncthreads();
    }
    int base = (tid == 0) ? 0 : sdata[tid - 1];
#pragma unroll
    for (int i = 0; i < 8; i++) row_ptr[tid * 8 + i] = base + local[i];
    if (tid == 1023) row_ptr[8192] = sdata[1023];
}

__global__ void copy_int_kernel(const int* __restrict__ a, int* __restrict__ b, int n) {
    int i = blockIdx.x * blockDim.x + threadIdx.x;
    if (i < n) b[i] = a[i];
}

__global__ void fill_kernel(const int* __restrict__ dst, const int* __restrict__ src,
                            int* __restrict__ cursor, int* __restrict__ eids,
                            int* __restrict__ gsrc, int E) {
    int e = blockIdx.x * blockDim.x + threadIdx.x;
    if (e < E) {
        int pos = atomicAdd(&cursor[dst[e]], 1);
        eids[pos] = e;
        gsrc[pos] = src[e];
    }
}

// ---------------------------------------------- fused fp32 -> bf16x2 splits
struct SplitArgs {
    const float* src[11];
    u16* hi[11];
    u16* lo[11];
    int  off[12];
};
__global__ __launch_bounds__(256) void multisplit_kernel(SplitArgs a) {
    int blk = blockIdx.x;
    int s = 0;
#pragma unroll
    for (int t = 0; t < 11; ++t) if (blk >= a.off[t + 1]) s = t + 1;
    size_t i = ((size_t)(blk - a.off[s]) * 256 + threadIdx.x) * 4;
    float4 v = *(const float4*)(a.src[s] + i);
    store_split4(a.hi[s], a.lo[s], i, v);
}

// transpose + split: out[c][r] planes from W[r][c]
__global__ void wtrans_split_kernel(const float* __restrict__ W, u16* __restrict__ outh,
                                    u16* __restrict__ outl, int R, int Cc) {
    int j = blockIdx.x * 256 + threadIdx.x;
    if (j >= R * Cc) return;
    int r = j % R, c = j / R;
    u16 h, l;
    split1(W[(size_t)r * Cc + c], h, l);
    outh[j] = h; outl[j] = l;
}

// ------------------- L2-blocked wave-per-node segment sums (128-feat halves)
// 2 edge slots x 4-deep (needs only >=8 edges/slot for the pipelined loop).
struct SegDuo {
    const float* T0; u16* oh0; u16* ol0; int self0;
    const float* T1; u16* oh1; u16* ol1; int self1; int nb0;
};
__global__ __launch_bounds__(256) void segsum128_wave_kernel(const int* __restrict__ row_ptr,
                                                             const int* __restrict__ idx,
                                                             SegDuo a) {
    int blk  = blockIdx.x;
    int seg  = blk / a.nb0;              // 0..3
    int lblk = blk - seg * a.nb0;
    const float* T; u16* oh; u16* ol; int self;
    if (seg >> 1) { T = a.T1; oh = a.oh1; ol = a.ol1; self = a.self1; }
    else          { T = a.T0; oh = a.oh0; ol = a.ol0; self = a.self0; }
    const int half = seg & 1;
    const int n    = lblk * 4 + (threadIdx.x >> 6);
    const int lane = threadIdx.x & 63;
    const int slot = lane >> 5;          // 0/1
    const size_t fo = (size_t)half * 128 + (size_t)(lane & 31) * 4;
    const int b = row_ptr[n], e = row_ptr[n + 1];
    float4 z4 = make_float4(0.f, 0.f, 0.f, 0.f);
    float4 a0 = z4, a1 = z4, a2 = z4, a3 = z4;
    int i = b + slot;
    for (; i + 6 < e; i += 8) {          // this slot: edges i, i+2, i+4, i+6
        int s0 = idx[i], s1 = idx[i + 2], s2 = idx[i + 4], s3 = idx[i + 6];
        add4(a0, *(const float4*)(T + (size_t)s0 * HD + fo));
        add4(a1, *(const float4*)(T + (size_t)s1 * HD + fo));
        add4(a2, *(const float4*)(T + (size_t)s2 * HD + fo));
        add4(a3, *(const float4*)(T + (size_t)s3 * HD + fo));
    }
    for (; i < e; i += 2) {
        int s0 = idx[i];
        add4(a0, *(const float4*)(T + (size_t)s0 * HD + fo));
    }
    if (self && slot == 0) add4(a1, *(const float4*)(T + (size_t)n * HD + fo));
    add4(a0, a1); add4(a2, a3); add4(a0, a2);
    a0.x += __shfl_xor(a0.x, 32); a0.y += __shfl_xor(a0.y, 32);
    a0.z += __shfl_xor(a0.z, 32); a0.w += __shfl_xor(a0.w, 32);
    if (slot == 0) store_split4(oh, ol, (size_t)n * HD + fo, a0);
}

// 64-feat: wave per node, 4 edge-groups of 16 lanes, shfl_xor reduce.
__global__ __launch_bounds__(256) void segsum64_wave_kernel(const int* __restrict__ row_ptr,
                                                            const int* __restrict__ idx,
                                                            const float* __restrict__ T,
                                                            u16* __restrict__ outh,
                                                            u16* __restrict__ outl) {
    const int n    = blockIdx.x * 4 + (threadIdx.x >> 6);
    const int lane = threadIdx.x & 63;
    const int g    = lane >> 4;
    const size_t fo = (size_t)(lane & 15) * 4;
    const int b = row_ptr[n], e = row_ptr[n + 1];
    float4 a0 = make_float4(0.f, 0.f, 0.f, 0.f);
    float4 a1 = a0;
    int i = b + g;
    for (; i + 4 < e; i += 8) {
        int s0 = idx[i], s1 = idx[i + 4];
        add4(a0, *(const float4*)(T + (size_t)s0 * 64 + fo));
        add4(a1, *(const float4*)(T + (size_t)s1 * 64 + fo));
    }
    if (i < e) {
        int s0 = idx[i];
        add4(a0, *(const float4*)(T + (size_t)s0 * 64 + fo));
    }
    add4(a0, a1);
    a0.x += __shfl_xor(a0.x, 16); a0.y += __shfl_xor(a0.y, 16);
    a0.z += __shfl_xor(a0.z, 16); a0.w += __shfl_xor(a0.w, 16);
    a0.x += __shfl_xor(a0.x, 32); a0.y += __shfl_xor(a0.y, 32);
    a0.z += __shfl_xor(a0.z, 32); a0.w += __shfl_xor(a0.w, 32);
    if (g == 0) store_split4(outh, outl, (size_t)n * 64 + fo, a0);
}

// ---------------- batched LDS-staged split-bf16 3-product MFMA GEMM
// 128x64 C-tile, 4 waves of 64x32. BK=64. LDS stride 64 u16 + XOR swizzle.
// Staging via global_load_lds width=16 with pre-swizzled global source (m173).
// Pipeline per tile: read ks0 frags -> MFMA ks0 -> read ks1 frags -> barrier
// -> stage(t+1) (overlaps) -> MFMA ks1.
// flags: 1 = relu, 2 = accumulate into C (skip bias)
struct GDesc {
    const u16 *Ah, *Al, *Abh, *Abl, *Wh, *Wl;
    const float* bias;
    float* C; u16 *Chi, *Clo;
    int lda, ldab, Ka, Kb, ldw, ldc, M, flags, nbx, nblk;
};
struct GBatch { GDesc d[3]; int start[4]; };

#define LDSA0 0
#define LDSA1 8192
#define LDSW0 16384
#define LDSW1 20480
__global__ __launch_bounds__(256) void hgemm_kernel(GBatch b) {
    __shared__ __align__(16) u16 lds[24576];
    int s = (blockIdx.x >= (unsigned)b.start[1]) + (blockIdx.x >= (unsigned)b.start[2]);
    GDesc d = b.d[0];
    if (s == 1) d = b.d[1];
    else if (s == 2) d = b.d[2];

    // local bijective XCD swizzle within this desc's block range
    int nwg = b.start[s + 1] - b.start[s];
    int o   = blockIdx.x - b.start[s];
    int q = nwg >> 3, r = nwg & 7;
    int xcd = o & 7;
    int base = (xcd < r) ? xcd * (q + 1) : r * (q + 1) + (xcd - r) * q;
    int wg = base + (o >> 3);
    int bx = wg % d.nbx, by = wg / d.nbx;

    const int tid  = threadIdx.x;
    const int wid  = tid >> 6;
    const int lane = tid & 63;
    const int lrow = lane & 15;
    const int ksel = lane >> 4;
    const int rswz = (lrow & 7) << 3;

    // gload_lds staging geometry: chunk j = i*256 + tid; row=j>>3; c_dst=lane&7
    const int arow_l = wid * 8 + (lane >> 3);            // + i*32 per issue
    const int csrc8  = ((lane & 7) ^ ((lane >> 3) & 7)) * 8;  // u16 offset of source chunk

    const int nt = (d.Ka + d.Kb) >> 6;

    auto stage = [&](int t) {
        int kb = t << 6;
        const u16 *ph, *pl; int ld_; int kk;
        if (kb < d.Ka) { ph = d.Ah;  pl = d.Al;  ld_ = d.lda;  kk = kb; }
        else           { ph = d.Abh; pl = d.Abl; ld_ = d.ldab; kk = kb - d.Ka; }
#pragma unroll
        for (int i = 0; i < 4; ++i) {
            int row = i * 32 + arow_l;
            int rg  = min(by * 128 + row, d.M - 1);
            const u16* gah = ph + (size_t)rg * ld_ + kk + csrc8;
            const u16* gal = pl + (size_t)rg * ld_ + kk + csrc8;
            char* ba = (char*)lds + i * 4096 + wid * 1024;
            __builtin_amdgcn_global_load_lds(GAS(gah), LAS(ba), 16, 0, 0);
            __builtin_amdgcn_global_load_lds(GAS(gal), LAS(ba + LDSA1 * 2), 16, 0, 0);
        }
#pragma unroll
        for (int i = 0; i < 2; ++i) {
            int row = i * 32 + arow_l;
            size_t wo = (size_t)(bx * 64 + row) * d.ldw + kb + csrc8;
            const u16* gwh = d.Wh + wo;
            const u16* gwl = d.Wl + wo;
            char* bw = (char*)lds + LDSW0 * 2 + i * 4096 + wid * 1024;
            __builtin_amdgcn_global_load_lds(GAS(gwh), LAS(bw), 16, 0, 0);
            __builtin_amdgcn_global_load_lds(GAS(gwl), LAS(bw + (LDSW1 - LDSW0) * 2), 16, 0, 0);
        }
    };

    f32x4 acc[4][2] = {};
    const int fr0 = (wid >> 1) * 64;
    const int cr0 = (wid & 1) * 32;

    bf16x8 fah[4], fal[4], fwh[2], fwl[2];
    auto readfr = [&](int ks) {
        const int ko = (ks * 32 + ksel * 8) ^ rswz;
#pragma unroll
        for (int fi = 0; fi < 4; ++fi) {
            int oo = (fr0 + fi * 16 + lrow) * 64 + ko;
            fah[fi] = *(const bf16x8*)(lds + LDSA0 + oo);
            fal[fi] = *(const bf16x8*)(lds + LDSA1 + oo);
        }
#pragma unroll
        for (int ci = 0; ci < 2; ++ci) {
            int oo = (cr0 + ci * 16 + lrow) * 64 + ko;
            fwh[ci] = *(const bf16x8*)(lds + LDSW0 + oo);
            fwl[ci] = *(const bf16x8*)(lds + LDSW1 + oo);
        }
    };
    auto mfmas = [&]() {
#pragma unroll
        for (int fi = 0; fi < 4; ++fi)
#pragma unroll
            for (int ci = 0; ci < 2; ++ci) {
                acc[fi][ci] = __builtin_amdgcn_mfma_f32_16x16x32_bf16(fah[fi], fwh[ci], acc[fi][ci], 0, 0, 0);
                acc[fi][ci] = __builtin_amdgcn_mfma_f32_16x16x32_bf16(fah[fi], fwl[ci], acc[fi][ci], 0, 0, 0);
                acc[fi][ci] = __builtin_amdgcn_mfma_f32_16x16x32_bf16(fal[fi], fwh[ci], acc[fi][ci], 0, 0, 0);
            }
    };

    stage(0);
    for (int t = 0; t < nt; ++t) {
        __syncthreads();          // stage(t) landed (vmcnt drained)
        readfr(0);
        mfmas();                  // ks0 on registers
        readfr(1);
        __syncthreads();          // all waves' ds_reads complete -> LDS free
        if (t + 1 < nt) stage(t + 1);   // latency hides under ks1 MFMAs
        mfmas();                  // ks1
    }

#pragma unroll
    for (int fi = 0; fi < 4; ++fi) {
        int rbase = by * 128 + fr0 + fi * 16 + (lane >> 4) * 4;
#pragma unroll
        for (int ci = 0; ci < 2; ++ci) {
            int col = bx * 64 + cr0 + ci * 16 + lrow;
#pragma unroll
            for (int j = 0; j < 4; ++j) {
                int rr = rbase + j;
                if (rr >= d.M) continue;
                float v = acc[fi][ci][j];
                size_t oo = (size_t)rr * d.ldc + col;
                if (d.flags & 2)    v += d.C[oo];
                else if (d.bias)    v += d.bias[col];
                if (d.flags & 1)    v = fmaxf(v, 0.f);
                if (d.C) d.C[oo] = v;
                if (d.Chi) { u16 hb, lb; split1(v, hb, lb); d.Chi[oo] = hb; d.Clo[oo] = lb; }
            }
        }
    }
}

// ----------------------------------------------------------- GRU elementwise
__global__ void gru_combine_kernel(const float* __restrict__ gi, const float* __restrict__ gh,
                                   const float* __restrict__ hprev, float* __restrict__ hout,
                                   u16* __restrict__ hhi, u16* __restrict__ hlo, int total4) {
    int t = blockIdx.x * 256 + threadIdx.x;
    if (t >= total4) return;
    int i4  = t * 4;
    int row = i4 >> 8, f = i4 & 255;
    size_t b = (size_t)row * 768;
    float4 ir = *(const float4*)(gi + b + f);
    float4 iz = *(const float4*)(gi + b + 256 + f);
    float4 in_ = *(const float4*)(gi + b + 512 + f);
    float4 hr = *(const float4*)(gh + b + f);
    float4 hz = *(const float4*)(gh + b + 256 + f);
    float4 hn = *(const float4*)(gh + b + 512 + f);
    float4 hp = *(const float4*)(hprev + (size_t)row * HD + f);
    float4 hv;
#pragma unroll
    for (int j = 0; j < 4; ++j) {
        float irj = ((const float*)&ir)[j], izj = ((const float*)&iz)[j], inj = ((const float*)&in_)[j];
        float hrj = ((const float*)&hr)[j], hzj = ((const float*)&hz)[j], hnj = ((const float*)&hn)[j];
        float r = 1.f / (1.f + expf(-(irj + hrj)));
        float z = 1.f / (1.f + expf(-(izj + hzj)));
        float n = tanhf(inj + r * hnj);
        ((float*)&hv)[j] = (1.f - z) * n + z * ((const float*)&hp)[j];
    }
    size_t o = (size_t)row * HD + f;
    *(float4*)(hout + o) = hv;
    if (hhi) store_split4(hhi, hlo, o, hv);
}

// ------------------------------------------------------------------ epilogue
__global__ void hhtail_kernel(const float* __restrict__ rc, const float* __restrict__ si,
                              float* __restrict__ hh, u16* __restrict__ hhi, u16* __restrict__ hlo) {
    int f = threadIdx.x;
    size_t o1 = (size_t)NN * HD + f, o2 = (size_t)(NN + 1) * HD + f;
    float a = rc[f], b = si[f];
    hh[o1] = a; hh[o2] = b;
    u16 h, l;
    split1(a, h, l); hhi[o1] = h; hlo[o1] = l;
    split1(b, h, l); hhi[o2] = h; hlo[o2] = l;
}

__global__ __launch_bounds__(256) void alpha_kernel(const float* __restrict__ g1, const float* __restrict__ gw2,
                                                    const float* __restrict__ gb2, const int* __restrict__ rcmask,
                                                    float* __restrict__ coef, int N) {
    int node = blockIdx.x * 4 + (threadIdx.x >> 6);
    int lane = threadIdx.x & 63;
    if (node >= N) return;
    float part = g1[(size_t)node * 128 + lane] * gw2[lane]
               + g1[(size_t)node * 128 + 64 + lane] * gw2[64 + lane];
    for (int off = 32; off > 0; off >>= 1) part += __shfl_down(part, off);
    if (lane == 0) {
        float a = 1.f / (1.f + expf(-(part + gb2[0])));
        coef[node] = rcmask[node] ? 0.f : a;
    }
}

__global__ __launch_bounds__(256) void colsum_kernel(const float* __restrict__ X, const float* __restrict__ coef,
                                                     float* __restrict__ out, int rows_total, int rows_per_blk) {
    int f  = threadIdx.x;
    int r0 = blockIdx.x * rows_per_blk;
    int r1 = r0 + rows_per_blk; if (r1 > rows_total) r1 = rows_total;
    float a0 = 0.f, a1 = 0.f;
    int r = r0;
    for (; r + 1 < r1; r += 2) {
        a0 += coef[r]     * X[(size_t)r * HD + f];
        a1 += coef[r + 1] * X[(size_t)(r + 1) * HD + f];
    }
    if (r < r1) a0 += coef[r] * X[(size_t)r * HD + f];
    atomicAdd(&out[f], a0 + a1);
}

__global__ __launch_bounds__(256) void gemv256_kernel(const float* __restrict__ M,
                                                      const float* __restrict__ vA,
                                                      const float* __restrict__ vB,
                                                      const float* __restrict__ bias,
                                                      float* __restrict__ out, int R) {
    int row  = blockIdx.x * 4 + (threadIdx.x >> 6);
    int lane = threadIdx.x & 63;
    if (row >= R) return;
    float4 v = *(const float4*)(vA + lane * 4);
    if (vB) {
        float4 b = *(const float4*)(vB + lane * 4);
        v.x += b.x; v.y += b.y; v.z += b.z; v.w += b.w;
    }
    float4 m = *(const float4*)(M + (size_t)row * 256 + lane * 4);
    float p = m.x * v.x + m.y * v.y + m.z * v.z + m.w * v.w;
    for (int off = 32; off > 0; off >>= 1) p += __shfl_down(p, off);
    if (lane == 0) out[row] = p + (bias ? bias[row] : 0.f);
}

__global__ void sgru_combine_kernel(const float* __restrict__ gi3, const float* __restrict__ gh3,
                                    const float* __restrict__ sinit,
                                    float* __restrict__ hh, u16* __restrict__ hhi, u16* __restrict__ hlo) {
    int f = threadIdx.x;
    float gir = gi3[f], giz = gi3[256 + f], gin_ = gi3[512 + f];
    float ghr = gh3[f], ghz = gh3[256 + f], ghn  = gh3[512 + f];
    float r = 1.f / (1.f + expf(-(gir + ghr)));
    float z = 1.f / (1.f + expf(-(giz + ghz)));
    float n = tanhf(gin_ + r * ghn);
    float hv = (1.f - z) * n + z * sinit[f];
    size_t o = (size_t)(NN + 1) * HD + f;
    hh[o] = hv;
    u16 h, l; split1(hv, h, l); hhi[o] = h; hlo[o] = l;
}

__global__ __launch_bounds__(256) void logits_kernel(const float* __restrict__ kall, const float* __restrict__ qrow,
                                                     float* __restrict__ logits, int n) {
    int j    = blockIdx.x * 4 + (threadIdx.x >> 6);
    int lane = threadIdx.x & 63;
    if (j >= n) return;
    float4 q = *(const float4*)(qrow + lane * 4);
    float4 k = *(const float4*)(kall + (size_t)j * HD + lane * 4);
    float part = q.x * k.x + q.y * k.y + q.z * k.z + q.w * k.w;
    for (int off = 32; off > 0; off >>= 1) part += __shfl_down(part, off);
    if (lane == 0) logits[j] = part * 0.0625f;
}

__global__ __launch_bounds__(1024) void softmax_prep_kernel(const float* __restrict__ logits, float* __restrict__ p,
                                                            float* __restrict__ scal, int n) {
    __shared__ float sd[1024];
    int tid = threadIdx.x;
    float mx = -1e30f;
    for (int j = tid; j < n; j += 1024) mx = fmaxf(mx, logits[j]);
    sd[tid] = mx;
    __syncthreads();
    for (int off = 512; off > 0; off >>= 1) { if (tid < off) sd[tid] = fmaxf(sd[tid], sd[tid + off]); __syncthreads(); }
    float m = sd[0];
    __syncthreads();
    float s = 0.f;
    for (int j = tid; j < n; j += 1024) { float e = expf(logits[j] - m); p[j] = e; s += e; }
    sd[tid] = s;
    __syncthreads();
    for (int off = 512; off > 0; off >>= 1) { if (tid < off) sd[tid] += sd[tid + off]; __syncthreads(); }
    if (tid == 0) scal[0] = sd[0];
}

__global__ __launch_bounds__(256) void final_gemv_kernel(const float* __restrict__ hh,
                                                         const float* __restrict__ ow,
                                                         const float* __restrict__ ob,
                                                         const float* __restrict__ ctx,
                                                         const float* __restrict__ scal,
                                                         float* __restrict__ out) {
    int row  = blockIdx.x * 4 + (threadIdx.x >> 6);
    int lane = threadIdx.x & 63;
    float4 c = *(const float4*)(ctx + lane * 4);
    float4 m = *(const float4*)(ow + (size_t)row * 256 + lane * 4);
    float p = m.x * c.x + m.y * c.y + m.z * c.z + m.w * c.w;
    for (int off = 32; off > 0; off >>= 1) p += __shfl_down(p, off);
    if (lane == 0) {
        float val = hh[(size_t)(NN + 1) * HD + row] + p / scal[0] + ob[row];
        out[row] = fmaxf(val, 0.f);
    }
}

// ---------------------------------------------------------------------------
extern "C" void kernel_launch(void* const* d_in, const int* in_sizes, int n_in,
                              void* d_out, int out_size, void* d_ws, size_t ws_size,
                              hipStream_t stream) {
    const float* x      = (const float*)d_in[0];
    const int*   ei     = (const int*)  d_in[1];
    const float* eattr  = (const float*)d_in[2];
    const int*   rcmask = (const int*)  d_in[3];
    const float* Wmsg1  = (const float*)d_in[4];
    const float* wih1   = (const float*)d_in[5];
    const float* whh1   = (const float*)d_in[6];
    const float* bih1   = (const float*)d_in[7];
    const float* bhh1   = (const float*)d_in[8];
    const float* Wmsg2  = (const float*)d_in[9];
    const float* wih2   = (const float*)d_in[10];
    const float* whh2   = (const float*)d_in[11];
    const float* bih2   = (const float*)d_in[12];
    const float* bhh2   = (const float*)d_in[13];
    const float* ginw1  = (const float*)d_in[14];
    const float* ginb1  = (const float*)d_in[15];
    const float* ginw2  = (const float*)d_in[16];
    const float* ginb2  = (const float*)d_in[17];
    const float* projw  = (const float*)d_in[18];
    const float* projb  = (const float*)d_in[19];
    const float* qw     = (const float*)d_in[20];
    const float* qb     = (const float*)d_in[21];
    const float* kw     = (const float*)d_in[22];
    const float* kb     = (const float*)d_in[23];
    const float* vw     = (const float*)d_in[24];
    const float* vb     = (const float*)d_in[25];
    const float* ow     = (const float*)d_in[26];
    const float* ob     = (const float*)d_in[27];
    const float* gatew1 = (const float*)d_in[28];
    const float* gateb1 = (const float*)d_in[29];
    const float* gatew2 = (const float*)d_in[30];
    const float* gateb2 = (const float*)d_in[31];
    const float* skipW  = (const float*)d_in[32];
    const float* swih   = (const float*)d_in[33];
    const float* swhh   = (const float*)d_in[34];
    const float* sbih   = (const float*)d_in[35];
    const float* sbhh   = (const float*)d_in[36];
    const float* rcinit = (const float*)d_in[37];
    const float* sinit  = (const float*)d_in[38];

    const int* src = ei;
    const int* dst = ei + NE;

    // ---------------- workspace layout -------------------------------------
    char*  w   = (char*)d_ws;
    size_t off = 0;
    auto alloc = [&](size_t bytes) -> void* {
        void* p = w + off;
        off = (off + bytes + 255) & ~(size_t)255;
        return p;
    };
    int*   cnt     = (int*)alloc((size_t)NN * 4);
    int*   row_ptr = (int*)alloc((size_t)(NN + 1) * 4);
    int*   eids    = (int*)alloc((size_t)NE * 4);
    int*   gsrc    = (int*)alloc((size_t)NE * 4);
    u16*   aeh     = (u16*)alloc((size_t)NN * 64 * 2);
    u16*   ael     = (u16*)alloc((size_t)NN * 64 * 2);
    u16*   shh_    = (u16*)alloc((size_t)NHH * HD * 2);    // x / hh planes
    u16*   shl_    = (u16*)alloc((size_t)NHH * HD * 2);
    u16*   gsh     = (u16*)alloc((size_t)NN * HD * 2);
    u16*   gsl     = (u16*)alloc((size_t)NN * HD * 2);
    u16*   gs2h    = (u16*)alloc((size_t)NN * HD * 2);
    u16*   gs2l    = (u16*)alloc((size_t)NN * HD * 2);
    u16*   msh     = (u16*)alloc((size_t)NN * HD * 2);
    u16*   msl     = (u16*)alloc((size_t)NN * HD * 2);
    u16*   ms2h    = (u16*)alloc((size_t)NN * HD * 2);
    u16*   ms2l    = (u16*)alloc((size_t)NN * HD * 2);
    float* h1      = (float*)alloc((size_t)NN * HD * 4);
    float* h2      = (float*)alloc((size_t)NN * HD * 4);
    float* gi      = (float*)alloc((size_t)NN * 768 * 4);  // gi fp32
    float* gh      = (float*)alloc((size_t)NN * 768 * 4);  // gh fp32; u768 planes / scratch / k,v
    float* hh      = (float*)alloc((size_t)NHH * HD * 4);
    float* coef    = (float*)alloc((size_t)NN * 4);
    float* wsum    = (float*)alloc(256 * 4);
    float* qrow    = (float*)alloc(256 * 4);
    float* logits  = (float*)alloc((size_t)NHH * 4);
    float* pbuf    = (float*)alloc((size_t)NHH * 4);
    float* scal    = (float*)alloc(256);
    float* ctx     = (float*)alloc(256 * 4);
    float* mvec    = (float*)alloc(256 * 4);
    float* gi3     = (float*)alloc(768 * 4);
    float* gh3     = (float*)alloc(768 * 4);

    auto walloc = [&](size_t nel, u16** h, u16** l) {
        *h = (u16*)alloc(nel * 2); *l = (u16*)alloc(nel * 2);
    };
    u16 *wm1Th, *wm1Tl, *wm2Th, *wm2Tl;
    u16 *wc1h, *wc1l, *wc2h, *wc2l;
    u16 *wi1h, *wi1l, *wh1h, *wh1l, *wi2h, *wi2l, *wh2h, *wh2l;
    u16 *g1h, *g1l, *g2h, *g2l, *pjh, *pjl, *gwh, *gwl, *kwh, *kwl, *vwh, *vwl;
    walloc(81920, &wm1Th, &wm1Tl); walloc(81920, &wm2Th, &wm2Tl);
    walloc(245760, &wc1h, &wc1l);  walloc(245760, &wc2h, &wc2l);
    walloc(196608, &wi1h, &wi1l);  walloc(196608, &wh1h, &wh1l);
    walloc(196608, &wi2h, &wi2l);  walloc(196608, &wh2h, &wh2l);
    walloc(196608, &g1h, &g1l);    walloc(196608, &g2h, &g2l);
    walloc(196608, &pjh, &pjl);    walloc(32768, &gwh, &gwl);
    walloc(65536, &kwh, &kwl);     walloc(65536, &vwh, &vwl);
    u16 *xh = shh_, *xl = shl_;

    // phase aliases (gh region: fp32 in DMPNN; u768 planes then scratch in GIN; k/v late)
    u16*   u768h = (u16*)gh;
    u16*   u768l = u768h + (size_t)NN * 768;
    u16*   sAh   = (u16*)gh;                       // scratch planes after u768 dead
    u16*   sAl   = sAh + (size_t)NN * HD;
    u16*   sBh   = sAh + (size_t)2 * NN * HD;
    u16*   sBl   = sAh + (size_t)3 * NN * HD;
    float* k_all = gh;
    float* v_all = gh + (size_t)NHH * HD;
    float* g1    = gh + (size_t)2 * NHH * HD;

    auto mkd = [&](const u16* Ah, const u16* Al, int lda,
                   const u16* Abh, const u16* Abl, int ldab, int Ka, int Kb,
                   const u16* Wh, const u16* Wl, int ldw, const float* bias,
                   float* C, u16* Chi, u16* Clo, int ldc,
                   int M, int Nc, int flags) -> GDesc {
        GDesc d;
        d.Ah = Ah; d.Al = Al; d.Abh = Abh; d.Abl = Abl; d.Wh = Wh; d.Wl = Wl;
        d.bias = bias; d.C = C; d.Chi = Chi; d.Clo = Clo;
        d.lda = lda; d.ldab = ldab; d.Ka = Ka; d.Kb = Kb; d.ldw = ldw; d.ldc = ldc;
        d.M = M; d.flags = flags; d.nbx = Nc / 64;
        d.nblk = d.nbx * ((M + 127) / 128);
        return d;
    };
    auto hg1 = [&](GDesc d0) {
        GBatch b; b.d[0] = d0; b.d[1] = d0; b.d[2] = d0;
        b.start[0] = 0; b.start[1] = d0.nblk; b.start[2] = d0.nblk; b.start[3] = d0.nblk;
        hgemm_kernel<<<b.start[3], 256, 0, stream>>>(b);
    };
    auto hg2 = [&](GDesc d0, GDesc d1) {
        GBatch b; b.d[0] = d0; b.d[1] = d1; b.d[2] = d1;
        b.start[0] = 0; b.start[1] = d0.nblk; b.start[2] = d0.nblk + d1.nblk; b.start[3] = b.start[2];
        hgemm_kernel<<<b.start[3], 256, 0, stream>>>(b);
    };
    auto hg3 = [&](GDesc d0, GDesc d1, GDesc d2) {
        GBatch b; b.d[0] = d0; b.d[1] = d1; b.d[2] = d2;
        b.start[0] = 0; b.start[1] = d0.nblk; b.start[2] = d0.nblk + d1.nblk;
        b.start[3] = b.start[2] + d2.nblk;
        hgemm_kernel<<<b.start[3], 256, 0, stream>>>(b);
    };
    auto seg1 = [&](const float* T, u16* oh, u16* ol, int self) {
        SegDuo a; a.T0 = T; a.oh0 = oh; a.ol0 = ol; a.self0 = self;
        a.T1 = T; a.oh1 = oh; a.ol1 = ol; a.self1 = self; a.nb0 = NN / 4;
        segsum128_wave_kernel<<<2 * (NN / 4), 256, 0, stream>>>(row_ptr, gsrc, a);
    };
    auto seg2 = [&](const float* T0, u16* oh0, u16* ol0, int s0,
                    const float* T1, u16* oh1, u16* ol1, int s1) {
        SegDuo a; a.T0 = T0; a.oh0 = oh0; a.ol0 = ol0; a.self0 = s0;
        a.T1 = T1; a.oh1 = oh1; a.ol1 = ol1; a.self1 = s1; a.nb0 = NN / 4;
        segsum128_wave_kernel<<<4 * (NN / 4), 256, 0, stream>>>(row_ptr, gsrc, a);
    };

    // ------------------------------ CSR build ------------------------------
    hipMemsetAsync(cnt, 0, (size_t)NN * 4, stream);
    hist_kernel<<<NE / 256, 256, 0, stream>>>(dst, cnt, NE);
    scan_kernel<<<1, 1024, 0, stream>>>(cnt, row_ptr);
    copy_int_kernel<<<NN / 256, 256, 0, stream>>>(row_ptr, cnt, NN);
    fill_kernel<<<NE / 256, 256, 0, stream>>>(dst, src, cnt, eids, gsrc, NE);
    segsum64_wave_kernel<<<NN / 4, 256, 0, stream>>>(row_ptr, eids, eattr, aeh, ael);

    // ------------------------------ one-time splits ------------------------
    {
        SplitArgs a;
        const float* srcs[11] = { x, wih1, whh1, wih2, whh2,
                                  ginw1, ginw2, projw, gatew1, kw, vw };
        u16* his[11] = { xh, wi1h, wh1h, wi2h, wh2h, g1h, g2h, pjh, gwh, kwh, vwh };
        u16* los[11] = { xl, wi1l, wh1l, wi2l, wh2l, g1l, g2l, pjl, gwl, kwl, vwl };
        const int blocks[11] = { 2048, 192, 192, 192, 192, 192, 192, 192, 32, 64, 64 };
        int acc = 0;
        for (int t = 0; t < 11; ++t) { a.src[t] = srcs[t]; a.hi[t] = his[t]; a.lo[t] = los[t]; a.off[t] = acc; acc += blocks[t]; }
        a.off[11] = acc;
        multisplit_kernel<<<acc, 256, 0, stream>>>(a);
    }
    wtrans_split_kernel<<<(81920 + 255) / 256, 256, 0, stream>>>(Wmsg1, wm1Th, wm1Tl, 256, 320);
    wtrans_split_kernel<<<(81920 + 255) / 256, 256, 0, stream>>>(Wmsg2, wm2Th, wm2Tl, 256, 320);
    // Wc = wih @ Wmsg   ([768][320] planes), both layers in one dispatch
    hg2(mkd(wi1h, wi1l, HD, nullptr, nullptr, 0, HD, 0, wm1Th, wm1Tl, HD, nullptr,
            nullptr, wc1h, wc1l, 320, 768, 320, 0),
        mkd(wi2h, wi2l, HD, nullptr, nullptr, 0, HD, 0, wm2Th, wm2Tl, HD, nullptr,
            nullptr, wc2h, wc2l, 320, 768, 320, 0));

    // ------------------------------ DMPNN 1 --------------------------------
    seg1(x, gsh, gsl, 0);
    hg2(mkd(gsh, gsl, HD, aeh, ael, 64, HD, 64, wc1h, wc1l, 320, bih1,
            gi, nullptr, nullptr, 768, NN, 768, 0),
        mkd(shh_, shl_, HD, nullptr, nullptr, 0, HD, 0, wh1h, wh1l, HD, bhh1,
            gh, nullptr, nullptr, 768, NN, 768, 0));
    gru_combine_kernel<<<NN * HD / 1024, 256, 0, stream>>>(gi, gh, x, h1, gs2h, gs2l, NN * HD / 4);

    // ------------------------------ DMPNN 2 --------------------------------
    seg1(h1, gsh, gsl, 0);
    hg2(mkd(gsh, gsl, HD, aeh, ael, 64, HD, 64, wc2h, wc2l, 320, bih2,
            gi, nullptr, nullptr, 768, NN, 768, 0),
        mkd(gs2h, gs2l, HD, nullptr, nullptr, 0, HD, 0, wh2h, wh2l, HD, bhh2,
            gh, nullptr, nullptr, 768, NN, 768, 0));
    gru_combine_kernel<<<NN * HD / 1024, 256, 0, stream>>>(gi, gh, h1, h2, nullptr, nullptr, NN * HD / 4);

    // ------------------------------ GIN towers (proj folded, batched) ------
    seg1(h2, gsh, gsl, 1);
    hg1(mkd(gsh, gsl, HD, nullptr, nullptr, 0, HD, 0, g1h, g1l, HD, ginb1,
            nullptr, u768h, u768l, 768, NN, 768, 1));
    hg3(mkd(u768h, u768l, 768, nullptr, nullptr, 0, HD, 0, g2h, g2l, HD, ginb2,
            nullptr, msh, msl, HD, NN, HD, 0),
        mkd(u768h + 256, u768l + 256, 768, nullptr, nullptr, 0, HD, 0, g2h + 65536, g2l + 65536, HD, ginb2 + 256,
            h1, nullptr, nullptr, HD, NN, HD, 0),
        mkd(u768h + 512, u768l + 512, 768, nullptr, nullptr, 0, HD, 0, g2h + 131072, g2l + 131072, HD, ginb2 + 512,
            h2, nullptr, nullptr, HD, NN, HD, 0));
    // towers 1,2 hop-2 aggregations (u768 now dead -> sA/sB scratch usable)
    seg2(h1, gsh, gsl, 1, h2, gs2h, gs2l, 1);
    // batch: proj slice 0 (reads msh) + g1 for towers 1,2 (write sA, sB)
    hg3(mkd(msh, msl, HD, nullptr, nullptr, 0, HD, 0, pjh, pjl, 768, projb,
            hh, nullptr, nullptr, HD, NN, HD, 0),
        mkd(gsh, gsl, HD, nullptr, nullptr, 0, HD, 0, g1h + 65536, g1l + 65536, HD, ginb1 + 256,
            nullptr, sAh, sAl, HD, NN, HD, 1),
        mkd(gs2h, gs2l, HD, nullptr, nullptr, 0, HD, 0, g1h + 131072, g1l + 131072, HD, ginb1 + 512,
            nullptr, sBh, sBl, HD, NN, HD, 1));
    // g2: tower1 final -> gsh planes, tower2 mid -> h1 fp32
    hg2(mkd(sAh, sAl, HD, nullptr, nullptr, 0, HD, 0, g2h + 65536, g2l + 65536, HD, ginb2 + 256,
            nullptr, gsh, gsl, HD, NN, HD, 0),
        mkd(sBh, sBl, HD, nullptr, nullptr, 0, HD, 0, g2h + 131072, g2l + 131072, HD, ginb2 + 512,
            h1, nullptr, nullptr, HD, NN, HD, 0));
    // tower2 hop-3 agg
    seg1(h1, gs2h, gs2l, 1);
    // batch: proj slice 1 (reads gsh, hh += ) + tower2 g1 (gs2 -> ms2)
    hg2(mkd(gsh, gsl, HD, nullptr, nullptr, 0, HD, 0, pjh + 256, pjl + 256, 768, nullptr,
            hh, nullptr, nullptr, HD, NN, HD, 2),
        mkd(gs2h, gs2l, HD, nullptr, nullptr, 0, HD, 0, g1h + 131072, g1l + 131072, HD, ginb1 + 512,
            nullptr, ms2h, ms2l, HD, NN, HD, 1));
    hg1(mkd(ms2h, ms2l, HD, nullptr, nullptr, 0, HD, 0, g2h + 131072, g2l + 131072, HD, ginb2 + 512,
            nullptr, gs2h, gs2l, HD, NN, HD, 0));
    // proj slice 2: hh += t2f @ projw[:, 512:768]^T ; emit hh planes
    hg1(mkd(gs2h, gs2l, HD, nullptr, nullptr, 0, HD, 0, pjh + 512, pjl + 512, 768, nullptr,
            hh, shh_, shl_, HD, NN, HD, 2));
    hhtail_kernel<<<1, 256, 0, stream>>>(rcinit, sinit, hh, shh_, shl_);

    // ------------------------------ gate / skip-sum / sGRU -----------------
    hg1(mkd(shh_, shl_, HD, nullptr, nullptr, 0, HD, 0, gwh, gwl, HD, gateb1,
            g1, nullptr, nullptr, 128, NN, 128, 1));
    alpha_kernel<<<NN / 4, 256, 0, stream>>>(g1, gatew2, gateb2, rcmask, coef, NN);
    hipMemsetAsync(wsum, 0, 256 * 4, stream);
    colsum_kernel<<<256, 256, 0, stream>>>(hh, coef, wsum, NN, 32);
    gemv256_kernel<<<64, 256, 0, stream>>>(skipW, wsum, rcinit, nullptr, mvec, 256);
    gemv256_kernel<<<192, 256, 0, stream>>>(swih, mvec, nullptr, sbih, gi3, 768);
    gemv256_kernel<<<192, 256, 0, stream>>>(swhh, sinit, nullptr, sbhh, gh3, 768);
    sgru_combine_kernel<<<1, 256, 0, stream>>>(gi3, gh3, sinit, hh, shh_, shl_);

    // ------------------------------ attention row --------------------------
    hg2(mkd(shh_, shl_, HD, nullptr, nullptr, 0, HD, 0, kwh, kwl, HD, kb,
            k_all, nullptr, nullptr, HD, NHH, HD, 0),
        mkd(shh_, shl_, HD, nullptr, nullptr, 0, HD, 0, vwh, vwl, HD, vb,
            v_all, nullptr, nullptr, HD, NHH, HD, 0));
    gemv256_kernel<<<64, 256, 0, stream>>>(qw, hh + (size_t)(NN + 1) * HD, nullptr, qb, qrow, 256);
    logits_kernel<<<(NHH + 3) / 4, 256, 0, stream>>>(k_all, qrow, logits, NHH);
    softmax_prep_kernel<<<1, 1024, 0, stream>>>(logits, pbuf, scal, NHH);
    hipMemsetAsync(ctx, 0, 256 * 4, stream);
    colsum_kernel<<<(NHH + 31) / 32, 256, 0, stream>>>(v_all, pbuf, ctx, NHH, 32);
    final_gemv_kernel<<<64, 256, 0, stream>>>(hh, ow, ob, ctx, scal, (float*)d_out);
}